// Round 1
// baseline (1004.887 us; speedup 1.0000x reference)
//
#include <hip/hip_runtime.h>
#include <stdint.h>

// Dims
#define NB 64
#define NL 64
#define NC 32
#define NK 100
#define NH 8
#define DKEY 16
#define DM 128
#define NG 128       // H*DKEY
#define DLLM 768
#define KP 4128      // 4096 + 32 (probs tail) : wout row stride
#define TEMP 0.25f   // 1/sqrt(16)

// ---------- bf16 helpers (manual, RNE) ----------
__device__ __forceinline__ uint16_t f2bf(float f) {
    union { float f; uint32_t i; } x; x.f = f;
    uint32_t r = x.i + 0x7FFFu + ((x.i >> 16) & 1u);
    return (uint16_t)(r >> 16);
}
__device__ __forceinline__ uint32_t pack2(float lo, float hi) {
    return (uint32_t)f2bf(lo) | ((uint32_t)f2bf(hi) << 16);
}
__device__ __forceinline__ void unpack2(uint32_t v, float& lo, float& hi) {
    union { uint32_t i; float f; } a, b;
    a.i = v << 16; b.i = v & 0xFFFF0000u;
    lo = a.f; hi = b.f;
}
__device__ __forceinline__ void unpack8(uint4 u, float* f) {
    unpack2(u.x, f[0], f[1]);
    unpack2(u.y, f[2], f[3]);
    unpack2(u.z, f[4], f[5]);
    unpack2(u.w, f[6], f[7]);
}

// ---------------------------------------------------------------------------
// Kernel 1: K/V projection.  k[c,kk,g] = dot(topk[c,kk,:], W[c,g,:768]) + W[c,g,768]
// Wave-dot: each wave computes an 8kk x 8g tile, lanes split the 768 K-dim.
// grid = 3328 blocks x 256 thr = 13312 wave-tiles = 2m * 32c * 13kt * 16gt
// ---------------------------------------------------------------------------
__global__ __launch_bounds__(256) void kv_proj_kernel(
    const float* __restrict__ topk,
    const float* __restrict__ Wk,
    const float* __restrict__ Wv,
    uint16_t* __restrict__ kbuf,
    uint16_t* __restrict__ vbuf)
{
    int wt = blockIdx.x * 4 + (threadIdx.x >> 6);
    int lane = threadIdx.x & 63;
    int gt = wt & 15; wt >>= 4;
    int kt = wt % 13; wt /= 13;
    int c  = wt & 31;
    int m  = wt >> 5;

    const float* W = (m == 0 ? Wk : Wv) + (size_t)c * (128 * 769);
    const float* T = topk + (size_t)c * (NK * DLLM);

    float acc[8][8];
#pragma unroll
    for (int i = 0; i < 8; ++i)
#pragma unroll
        for (int j = 0; j < 8; ++j) acc[i][j] = 0.0f;

    for (int dc = 0; dc < 12; ++dc) {
        int d = dc * 64 + lane;
        float a[8], w[8];
#pragma unroll
        for (int i = 0; i < 8; ++i) {
            int kk = kt * 8 + i;
            a[i] = (kk < NK) ? T[kk * DLLM + d] : 0.0f;
        }
#pragma unroll
        for (int j = 0; j < 8; ++j)
            w[j] = W[(gt * 8 + j) * 769 + d];
#pragma unroll
        for (int i = 0; i < 8; ++i)
#pragma unroll
            for (int j = 0; j < 8; ++j)
                acc[i][j] = fmaf(a[i], w[j], acc[i][j]);
    }

    float res = 0.0f;
#pragma unroll
    for (int i = 0; i < 8; ++i)
#pragma unroll
        for (int j = 0; j < 8; ++j) {
            float s = acc[i][j];
            s += __shfl_xor(s, 32);
            s += __shfl_xor(s, 16);
            s += __shfl_xor(s, 8);
            s += __shfl_xor(s, 4);
            s += __shfl_xor(s, 2);
            s += __shfl_xor(s, 1);
            if (lane == i * 8 + j) res = s;
        }

    int kk = kt * 8 + (lane >> 3);
    int g  = gt * 8 + (lane & 7);
    if (kk < NK) {
        float bias = W[g * 769 + 768];
        uint16_t* ob = (m == 0) ? kbuf : vbuf;
        ob[((size_t)c * NK + kk) * NG + g] = f2bf(res + bias);
    }
}

// ---------------------------------------------------------------------------
// Kernel 2: Q projection. q[c, b*64+l, g] = dot(ts[b,l,:], Wq[c,g,:128]) + Wq[c,g,128]
// LDS-tiled GEMM per (c,b): 64l x 128g output, thread tile 4x8, K-tile 32.
// grid = 2048 (c*64+b), 256 thr.
// ---------------------------------------------------------------------------
__global__ __launch_bounds__(256) void q_proj_kernel(
    const float* __restrict__ ts,
    const float* __restrict__ Wq,
    uint16_t* __restrict__ qbuf)
{
    __shared__ float tsT[32][64];    // [d][l]
    __shared__ float wqT[32][128];   // [d][g]

    int bid = blockIdx.x;
    int b = bid & 63;
    int c = bid >> 6;
    const float* Wc = Wq + (size_t)c * (128 * 129);
    const float* tb = ts + (size_t)b * (64 * 128);

    int tid = threadIdx.x;
    int gq = tid & 15;      // 16 groups of 8 g
    int mq = tid >> 4;      // 16 groups of 4 l

    float acc[4][8];
#pragma unroll
    for (int i = 0; i < 4; ++i)
#pragma unroll
        for (int j = 0; j < 8; ++j) acc[i][j] = 0.0f;

    int al  = tid >> 2;          // l 0..63
    int adq = (tid & 3) * 8;     // d sub-offset
    int wg  = tid >> 1;          // g 0..127
    int wdq = (tid & 1) * 16;

    for (int dt = 0; dt < 4; ++dt) {
        __syncthreads();
        {
            const float* src = tb + al * 128 + dt * 32 + adq;
            float4 v0 = *(const float4*)src;
            float4 v1 = *(const float4*)(src + 4);
            tsT[adq + 0][al] = v0.x; tsT[adq + 1][al] = v0.y;
            tsT[adq + 2][al] = v0.z; tsT[adq + 3][al] = v0.w;
            tsT[adq + 4][al] = v1.x; tsT[adq + 5][al] = v1.y;
            tsT[adq + 6][al] = v1.z; tsT[adq + 7][al] = v1.w;
        }
        {
            const float* src = Wc + wg * 129 + dt * 32 + wdq;
#pragma unroll
            for (int j = 0; j < 16; ++j) wqT[wdq + j][wg] = src[j];
        }
        __syncthreads();
#pragma unroll 8
        for (int d = 0; d < 32; ++d) {
            float a[4], bv[8];
            *(float4*)&a[0]  = *(const float4*)&tsT[d][mq * 4];
            *(float4*)&bv[0] = *(const float4*)&wqT[d][gq * 8];
            *(float4*)&bv[4] = *(const float4*)&wqT[d][gq * 8 + 4];
#pragma unroll
            for (int i = 0; i < 4; ++i)
#pragma unroll
                for (int j = 0; j < 8; ++j)
                    acc[i][j] = fmaf(a[i], bv[j], acc[i][j]);
        }
    }

    int gb = gq * 8;
    float bias[8];
#pragma unroll
    for (int j = 0; j < 8; ++j) bias[j] = Wc[(gb + j) * 129 + 128];

#pragma unroll
    for (int i = 0; i < 4; ++i) {
        int l = mq * 4 + i;
        uint4 u;
        u.x = pack2(acc[i][0] + bias[0], acc[i][1] + bias[1]);
        u.y = pack2(acc[i][2] + bias[2], acc[i][3] + bias[3]);
        u.z = pack2(acc[i][4] + bias[4], acc[i][5] + bias[5]);
        u.w = pack2(acc[i][6] + bias[6], acc[i][7] + bias[7]);
        *(uint4*)&qbuf[((size_t)c * 4096 + b * 64 + l) * 128 + gb] = u;
    }
}

// ---------------------------------------------------------------------------
// Kernel 3: fused attention.  Per block (b,c); thread = (h, group of 4 l).
// Direct softmax (no max-sub; logits bounded), output scaled by probs/sum,
// written as bf16 into wout[bl][c*128+hd]; probs tail in cols 4096+c.
// grid = 2048 (c*64+b), 128 thr.
// ---------------------------------------------------------------------------
__global__ __launch_bounds__(128) void attn_kernel(
    const uint16_t* __restrict__ qbuf,
    const uint16_t* __restrict__ kbuf,
    const uint16_t* __restrict__ vbuf,
    const float* __restrict__ probs,
    uint16_t* __restrict__ wout)
{
    int bid = blockIdx.x;
    int c = bid >> 6;
    int b = bid & 63;
    int tid = threadIdx.x;
    int h  = tid >> 4;
    int lq = tid & 15;

    float q[4][16];
    float o[4][16];
    float ssum[4] = {0.f, 0.f, 0.f, 0.f};
    float pr[4];

#pragma unroll
    for (int i = 0; i < 4; ++i) {
        int l = lq * 4 + i;
        pr[i] = probs[((size_t)b * 64 + l) * NC + c];
        const uint16_t* qp = qbuf + ((size_t)c * 4096 + b * 64 + l) * 128 + h * 16;
        uint4 u0 = *(const uint4*)qp;
        uint4 u1 = *(const uint4*)(qp + 8);
        unpack8(u0, &q[i][0]);
        unpack8(u1, &q[i][8]);
#pragma unroll
        for (int d = 0; d < 16; ++d) o[i][d] = 0.0f;
    }

    const uint16_t* kc = kbuf + (size_t)c * (NK * NG) + h * 16;
    const uint16_t* vc = vbuf + (size_t)c * (NK * NG) + h * 16;

    for (int kk = 0; kk < NK; ++kk) {
        float kv[16], vv[16];
        {
            uint4 a0 = *(const uint4*)(kc + kk * 128);
            uint4 a1 = *(const uint4*)(kc + kk * 128 + 8);
            unpack8(a0, kv); unpack8(a1, kv + 8);
            uint4 b0 = *(const uint4*)(vc + kk * 128);
            uint4 b1 = *(const uint4*)(vc + kk * 128 + 8);
            unpack8(b0, vv); unpack8(b1, vv + 8);
        }
#pragma unroll
        for (int i = 0; i < 4; ++i) {
            float s = 0.0f;
#pragma unroll
            for (int d = 0; d < 16; ++d) s = fmaf(q[i][d], kv[d], s);
            float p = __expf(s * TEMP);
            ssum[i] += p;
#pragma unroll
            for (int d = 0; d < 16; ++d) o[i][d] = fmaf(p, vv[d], o[i][d]);
        }
    }

#pragma unroll
    for (int i = 0; i < 4; ++i) {
        int l = lq * 4 + i;
        float sc = pr[i] / ssum[i];
        uint4 u0, u1;
        u0.x = pack2(o[i][0] * sc,  o[i][1] * sc);
        u0.y = pack2(o[i][2] * sc,  o[i][3] * sc);
        u0.z = pack2(o[i][4] * sc,  o[i][5] * sc);
        u0.w = pack2(o[i][6] * sc,  o[i][7] * sc);
        u1.x = pack2(o[i][8] * sc,  o[i][9] * sc);
        u1.y = pack2(o[i][10] * sc, o[i][11] * sc);
        u1.z = pack2(o[i][12] * sc, o[i][13] * sc);
        u1.w = pack2(o[i][14] * sc, o[i][15] * sc);
        uint16_t* wp = wout + ((size_t)b * 64 + l) * KP + c * 128 + h * 16;
        *(uint4*)wp       = u0;
        *(uint4*)(wp + 8) = u1;
    }
    if (h == 0) {
#pragma unroll
        for (int i = 0; i < 4; ++i) {
            int l = lq * 4 + i;
            wout[((size_t)b * 64 + l) * KP + 4096 + c] = f2bf(pr[i]);
        }
    }
}

// ---------------------------------------------------------------------------
// Kernel 4: final GEMM.  out[4096,768] = wout(bf16)[4096,4128] @ [Wo;bo][4128,768]
// Block tile 64m x 128n, 128 thr, thread tile 8x8, K-tile 32. grid = 64*6=384.
// ---------------------------------------------------------------------------
__global__ __launch_bounds__(128) void fgemm_kernel(
    const uint16_t* __restrict__ wout,
    const float* __restrict__ Wo,
    const float* __restrict__ bo,
    float* __restrict__ out)
{
    __shared__ float AsT[32][64];    // [kk][m]
    __shared__ float Bs[32][128];    // [kk][n]

    int bid = blockIdx.x;
    int nb = bid % 6;
    int mb = bid / 6;
    int tid = threadIdx.x;
    int gq = tid & 15;   // n-group of 8
    int mq = tid >> 4;   // m-group of 8 (0..7)

    float acc[8][8];
#pragma unroll
    for (int i = 0; i < 8; ++i)
#pragma unroll
        for (int j = 0; j < 8; ++j) acc[i][j] = 0.0f;

    int am  = tid >> 1;           // m 0..63
    int akq = (tid & 1) * 16;     // kk 0/16
    int bk  = tid >> 2;           // kk 0..31
    int bn  = (tid & 3) * 32;     // n 0,32,64,96

    for (int kt = 0; kt < 129; ++kt) {
        __syncthreads();
        {
            const uint16_t* ap = wout + ((size_t)mb * 64 + am) * KP + kt * 32 + akq;
            uint4 u0 = *(const uint4*)ap;
            uint4 u1 = *(const uint4*)(ap + 8);
            float f[16];
            unpack8(u0, f); unpack8(u1, f + 8);
#pragma unroll
            for (int j = 0; j < 16; ++j) AsT[akq + j][am] = f[j];
        }
        {
            int kg = kt * 32 + bk;
            const float* bp = (kg < 4096) ? (Wo + (size_t)kg * DLLM)
                                          : (bo + (size_t)(kg - 4096) * DLLM);
            bp += nb * 128 + bn;
#pragma unroll
            for (int j = 0; j < 8; ++j) {
                float4 v = *(const float4*)(bp + j * 4);
                *(float4*)&Bs[bk][bn + j * 4] = v;
            }
        }
        __syncthreads();
#pragma unroll 8
        for (int d = 0; d < 32; ++d) {
            float a[8], bv[8];
            *(float4*)&a[0]  = *(const float4*)&AsT[d][mq * 8];
            *(float4*)&a[4]  = *(const float4*)&AsT[d][mq * 8 + 4];
            *(float4*)&bv[0] = *(const float4*)&Bs[d][gq * 8];
            *(float4*)&bv[4] = *(const float4*)&Bs[d][gq * 8 + 4];
#pragma unroll
            for (int i = 0; i < 8; ++i)
#pragma unroll
                for (int j = 0; j < 8; ++j)
                    acc[i][j] = fmaf(a[i], bv[j], acc[i][j]);
        }
    }

#pragma unroll
    for (int i = 0; i < 8; ++i) {
        int m = mb * 64 + mq * 8 + i;
        float* op = out + (size_t)m * DLLM + nb * 128 + gq * 8;
        *(float4*)op       = make_float4(acc[i][0], acc[i][1], acc[i][2], acc[i][3]);
        *(float4*)(op + 4) = make_float4(acc[i][4], acc[i][5], acc[i][6], acc[i][7]);
    }
}

// ---------------------------------------------------------------------------
extern "C" void kernel_launch(void* const* d_in, const int* in_sizes, int n_in,
                              void* d_out, int out_size, void* d_ws, size_t ws_size,
                              hipStream_t stream) {
    const float* topk  = (const float*)d_in[0];  // (32,100,768)
    const float* ts    = (const float*)d_in[1];  // (64,64,128)
    const float* probs = (const float*)d_in[2];  // (64,64,32)
    const float* Wq    = (const float*)d_in[3];  // (32,128,129)
    const float* Wk    = (const float*)d_in[4];  // (32,128,769)
    const float* Wv    = (const float*)d_in[5];  // (32,128,769)
    const float* Wo    = (const float*)d_in[6];  // (32,128,768)
    const float* bo    = (const float*)d_in[7];  // (32,768)
    float* out = (float*)d_out;

    // workspace layout (bf16 / uint16): kbuf | vbuf | qbuf | wout  (~69 MB)
    uint16_t* ws   = (uint16_t*)d_ws;
    uint16_t* kbuf = ws;                           // 32*100*128   = 409600
    uint16_t* vbuf = ws + 409600;                  // 409600
    uint16_t* qbuf = ws + 819200;                  // 32*4096*128  = 16777216
    uint16_t* wout = ws + 819200 + 16777216;       // 4096*4128    = 16904192

    kv_proj_kernel<<<3328, 256, 0, stream>>>(topk, Wk, Wv, kbuf, vbuf);
    q_proj_kernel<<<2048, 256, 0, stream>>>(ts, Wq, qbuf);
    attn_kernel<<<2048, 128, 0, stream>>>(qbuf, kbuf, vbuf, probs, wout);
    fgemm_kernel<<<384, 128, 0, stream>>>(wout, Wo, bo, out);
}

// Round 2
// 342.145 us; speedup vs baseline: 2.9370x; 2.9370x over previous
//
#include <hip/hip_runtime.h>
#include <stdint.h>

// Dims
#define NB 64
#define NL 64
#define NC 32
#define NK 100
#define NH 8
#define DKEY 16
#define DM 128
#define NG 128       // H*DKEY
#define DLLM 768
#define KP 4128      // 4096 + 32 (probs tail) : wout row stride
#define TEMP 0.25f   // 1/sqrt(16)

typedef __attribute__((ext_vector_type(8))) short bf16x8;
typedef __attribute__((ext_vector_type(4))) float f32x4;

typedef uint32_t __attribute__((address_space(1))) gu32;
typedef uint32_t __attribute__((address_space(3))) lu32;

__device__ __forceinline__ void gload_lds16(const void* g, void* l) {
    __builtin_amdgcn_global_load_lds((const gu32*)g, (lu32*)l, 16, 0, 0);
}

// ---------- bf16 helpers (manual, RNE) ----------
__device__ __forceinline__ uint16_t f2bf(float f) {
    union { float f; uint32_t i; } x; x.f = f;
    uint32_t r = x.i + 0x7FFFu + ((x.i >> 16) & 1u);
    return (uint16_t)(r >> 16);
}
__device__ __forceinline__ uint32_t pack2(float lo, float hi) {
    return (uint32_t)f2bf(lo) | ((uint32_t)f2bf(hi) << 16);
}
__device__ __forceinline__ void unpack2(uint32_t v, float& lo, float& hi) {
    union { uint32_t i; float f; } a, b;
    a.i = v << 16; b.i = v & 0xFFFF0000u;
    lo = a.f; hi = b.f;
}
__device__ __forceinline__ void unpack8(uint4 u, float* f) {
    unpack2(u.x, f[0], f[1]);
    unpack2(u.y, f[2], f[3]);
    unpack2(u.z, f[4], f[5]);
    unpack2(u.w, f[6], f[7]);
}

// ---------------------------------------------------------------------------
// Kernel 1: K/V projection (unchanged from round 0).
// ---------------------------------------------------------------------------
__global__ __launch_bounds__(256) void kv_proj_kernel(
    const float* __restrict__ topk,
    const float* __restrict__ Wk,
    const float* __restrict__ Wv,
    uint16_t* __restrict__ kbuf,
    uint16_t* __restrict__ vbuf)
{
    int wt = blockIdx.x * 4 + (threadIdx.x >> 6);
    int lane = threadIdx.x & 63;
    int gt = wt & 15; wt >>= 4;
    int kt = wt % 13; wt /= 13;
    int c  = wt & 31;
    int m  = wt >> 5;

    const float* W = (m == 0 ? Wk : Wv) + (size_t)c * (128 * 769);
    const float* T = topk + (size_t)c * (NK * DLLM);

    float acc[8][8];
#pragma unroll
    for (int i = 0; i < 8; ++i)
#pragma unroll
        for (int j = 0; j < 8; ++j) acc[i][j] = 0.0f;

    for (int dc = 0; dc < 12; ++dc) {
        int d = dc * 64 + lane;
        float a[8], w[8];
#pragma unroll
        for (int i = 0; i < 8; ++i) {
            int kk = kt * 8 + i;
            a[i] = (kk < NK) ? T[kk * DLLM + d] : 0.0f;
        }
#pragma unroll
        for (int j = 0; j < 8; ++j)
            w[j] = W[(gt * 8 + j) * 769 + d];
#pragma unroll
        for (int i = 0; i < 8; ++i)
#pragma unroll
            for (int j = 0; j < 8; ++j)
                acc[i][j] = fmaf(a[i], w[j], acc[i][j]);
    }

    float res = 0.0f;
#pragma unroll
    for (int i = 0; i < 8; ++i)
#pragma unroll
        for (int j = 0; j < 8; ++j) {
            float s = acc[i][j];
            s += __shfl_xor(s, 32);
            s += __shfl_xor(s, 16);
            s += __shfl_xor(s, 8);
            s += __shfl_xor(s, 4);
            s += __shfl_xor(s, 2);
            s += __shfl_xor(s, 1);
            if (lane == i * 8 + j) res = s;
        }

    int kk = kt * 8 + (lane >> 3);
    int g  = gt * 8 + (lane & 7);
    if (kk < NK) {
        float bias = W[g * 769 + 768];
        uint16_t* ob = (m == 0) ? kbuf : vbuf;
        ob[((size_t)c * NK + kk) * NG + g] = f2bf(res + bias);
    }
}

// ---------------------------------------------------------------------------
// Kernel 2: Q projection (unchanged from round 0).
// ---------------------------------------------------------------------------
__global__ __launch_bounds__(256) void q_proj_kernel(
    const float* __restrict__ ts,
    const float* __restrict__ Wq,
    uint16_t* __restrict__ qbuf)
{
    __shared__ float tsT[32][64];    // [d][l]
    __shared__ float wqT[32][128];   // [d][g]

    int bid = blockIdx.x;
    int b = bid & 63;
    int c = bid >> 6;
    const float* Wc = Wq + (size_t)c * (128 * 129);
    const float* tb = ts + (size_t)b * (64 * 128);

    int tid = threadIdx.x;
    int gq = tid & 15;
    int mq = tid >> 4;

    float acc[4][8];
#pragma unroll
    for (int i = 0; i < 4; ++i)
#pragma unroll
        for (int j = 0; j < 8; ++j) acc[i][j] = 0.0f;

    int al  = tid >> 2;
    int adq = (tid & 3) * 8;
    int wg  = tid >> 1;
    int wdq = (tid & 1) * 16;

    for (int dt = 0; dt < 4; ++dt) {
        __syncthreads();
        {
            const float* src = tb + al * 128 + dt * 32 + adq;
            float4 v0 = *(const float4*)src;
            float4 v1 = *(const float4*)(src + 4);
            tsT[adq + 0][al] = v0.x; tsT[adq + 1][al] = v0.y;
            tsT[adq + 2][al] = v0.z; tsT[adq + 3][al] = v0.w;
            tsT[adq + 4][al] = v1.x; tsT[adq + 5][al] = v1.y;
            tsT[adq + 6][al] = v1.z; tsT[adq + 7][al] = v1.w;
        }
        {
            const float* src = Wc + wg * 129 + dt * 32 + wdq;
#pragma unroll
            for (int j = 0; j < 16; ++j) wqT[wdq + j][wg] = src[j];
        }
        __syncthreads();
#pragma unroll 8
        for (int d = 0; d < 32; ++d) {
            float a[4], bv[8];
            *(float4*)&a[0]  = *(const float4*)&tsT[d][mq * 4];
            *(float4*)&bv[0] = *(const float4*)&wqT[d][gq * 8];
            *(float4*)&bv[4] = *(const float4*)&wqT[d][gq * 8 + 4];
#pragma unroll
            for (int i = 0; i < 4; ++i)
#pragma unroll
                for (int j = 0; j < 8; ++j)
                    acc[i][j] = fmaf(a[i], bv[j], acc[i][j]);
        }
    }

    int gb = gq * 8;
    float bias[8];
#pragma unroll
    for (int j = 0; j < 8; ++j) bias[j] = Wc[(gb + j) * 129 + 128];

#pragma unroll
    for (int i = 0; i < 4; ++i) {
        int l = mq * 4 + i;
        uint4 u;
        u.x = pack2(acc[i][0] + bias[0], acc[i][1] + bias[1]);
        u.y = pack2(acc[i][2] + bias[2], acc[i][3] + bias[3]);
        u.z = pack2(acc[i][4] + bias[4], acc[i][5] + bias[5]);
        u.w = pack2(acc[i][6] + bias[6], acc[i][7] + bias[7]);
        *(uint4*)&qbuf[((size_t)c * 4096 + b * 64 + l) * 128 + gb] = u;
    }
}

// ---------------------------------------------------------------------------
// Kernel 3: fused attention (unchanged from round 0).
// ---------------------------------------------------------------------------
__global__ __launch_bounds__(128) void attn_kernel(
    const uint16_t* __restrict__ qbuf,
    const uint16_t* __restrict__ kbuf,
    const uint16_t* __restrict__ vbuf,
    const float* __restrict__ probs,
    uint16_t* __restrict__ wout)
{
    int bid = blockIdx.x;
    int c = bid >> 6;
    int b = bid & 63;
    int tid = threadIdx.x;
    int h  = tid >> 4;
    int lq = tid & 15;

    float q[4][16];
    float o[4][16];
    float ssum[4] = {0.f, 0.f, 0.f, 0.f};
    float pr[4];

#pragma unroll
    for (int i = 0; i < 4; ++i) {
        int l = lq * 4 + i;
        pr[i] = probs[((size_t)b * 64 + l) * NC + c];
        const uint16_t* qp = qbuf + ((size_t)c * 4096 + b * 64 + l) * 128 + h * 16;
        uint4 u0 = *(const uint4*)qp;
        uint4 u1 = *(const uint4*)(qp + 8);
        unpack8(u0, &q[i][0]);
        unpack8(u1, &q[i][8]);
#pragma unroll
        for (int d = 0; d < 16; ++d) o[i][d] = 0.0f;
    }

    const uint16_t* kc = kbuf + (size_t)c * (NK * NG) + h * 16;
    const uint16_t* vc = vbuf + (size_t)c * (NK * NG) + h * 16;

    for (int kk = 0; kk < NK; ++kk) {
        float kv[16], vv[16];
        {
            uint4 a0 = *(const uint4*)(kc + kk * 128);
            uint4 a1 = *(const uint4*)(kc + kk * 128 + 8);
            unpack8(a0, kv); unpack8(a1, kv + 8);
            uint4 b0 = *(const uint4*)(vc + kk * 128);
            uint4 b1 = *(const uint4*)(vc + kk * 128 + 8);
            unpack8(b0, vv); unpack8(b1, vv + 8);
        }
#pragma unroll
        for (int i = 0; i < 4; ++i) {
            float s = 0.0f;
#pragma unroll
            for (int d = 0; d < 16; ++d) s = fmaf(q[i][d], kv[d], s);
            float p = __expf(s * TEMP);
            ssum[i] += p;
#pragma unroll
            for (int d = 0; d < 16; ++d) o[i][d] = fmaf(p, vv[d], o[i][d]);
        }
    }

#pragma unroll
    for (int i = 0; i < 4; ++i) {
        int l = lq * 4 + i;
        float sc = pr[i] / ssum[i];
        uint4 u0, u1;
        u0.x = pack2(o[i][0] * sc,  o[i][1] * sc);
        u0.y = pack2(o[i][2] * sc,  o[i][3] * sc);
        u0.z = pack2(o[i][4] * sc,  o[i][5] * sc);
        u0.w = pack2(o[i][6] * sc,  o[i][7] * sc);
        u1.x = pack2(o[i][8] * sc,  o[i][9] * sc);
        u1.y = pack2(o[i][10] * sc, o[i][11] * sc);
        u1.z = pack2(o[i][12] * sc, o[i][13] * sc);
        u1.w = pack2(o[i][14] * sc, o[i][15] * sc);
        uint16_t* wp = wout + ((size_t)b * 64 + l) * KP + c * 128 + h * 16;
        *(uint4*)wp       = u0;
        *(uint4*)(wp + 8) = u1;
    }
    if (h == 0) {
#pragma unroll
        for (int i = 0; i < 4; ++i) {
            int l = lq * 4 + i;
            wout[((size_t)b * 64 + l) * KP + 4096 + c] = f2bf(pr[i]);
        }
    }
}

// ---------------------------------------------------------------------------
// Kernel 4a: transpose+convert [Wo;bo] fp32 [4128][768] -> WoBT bf16 [768][4128]
// 32k x 64n tiles via LDS; grid = 129*12 = 1548, 256 thr.
// ---------------------------------------------------------------------------
__global__ __launch_bounds__(256) void convert_wo_kernel(
    const float* __restrict__ Wo,
    const float* __restrict__ bo,
    uint16_t* __restrict__ wobt)
{
    __shared__ float tile[32][65];
    int bid = blockIdx.x;
    int kt = bid / 12;       // 0..128
    int nb = bid % 12;
    int t = threadIdx.x;
    {
        int rr = t >> 3;         // 0..31
        int c0 = (t & 7) * 8;    // 0..56
        int kg = kt * 32 + rr;
        const float* src = (kg < 4096 ? Wo + (size_t)kg * DLLM
                                      : bo + (size_t)(kg - 4096) * DLLM)
                           + nb * 64 + c0;
        float4 v0 = *(const float4*)src;
        float4 v1 = *(const float4*)(src + 4);
        tile[rr][c0 + 0] = v0.x; tile[rr][c0 + 1] = v0.y;
        tile[rr][c0 + 2] = v0.z; tile[rr][c0 + 3] = v0.w;
        tile[rr][c0 + 4] = v1.x; tile[rr][c0 + 5] = v1.y;
        tile[rr][c0 + 6] = v1.z; tile[rr][c0 + 7] = v1.w;
    }
    __syncthreads();
    {
        int n  = t >> 2;         // 0..63
        int k0 = (t & 3) * 8;    // 0,8,16,24
        uint4 u;
        u.x = pack2(tile[k0 + 0][n], tile[k0 + 1][n]);
        u.y = pack2(tile[k0 + 2][n], tile[k0 + 3][n]);
        u.z = pack2(tile[k0 + 4][n], tile[k0 + 5][n]);
        u.w = pack2(tile[k0 + 6][n], tile[k0 + 7][n]);
        *(uint4*)&wobt[((size_t)(nb * 64 + n)) * KP + kt * 32 + k0] = u;
    }
}

// ---------------------------------------------------------------------------
// Kernel 4b: MFMA GEMM. out[4096,768] = wout(bf16)[4096,4128] @ WoBT^T
// 64x64 block tile, 4 waves (2x2), 2x2 16x16x32 fragments per wave.
// Fragment-major LDS layout: frag read = base + lane*16B (conflict-free).
// Staging via global_load_lds width 16, double-buffered, 1 barrier/K-step.
// grid = 64*12 = 768 blocks (3/CU), XCD-swizzled.
// ---------------------------------------------------------------------------
__global__ __launch_bounds__(256) void fgemm_mfma_kernel(
    const uint16_t* __restrict__ wout,   // A  [4096][4128] bf16
    const uint16_t* __restrict__ wobt,   // B^T [768][4128] bf16
    float* __restrict__ out)             // [4096][768] fp32
{
    // [buf][rowgroup g(4)][kchunk(4)][row16][8 bf16] : 2048 shorts per buf
    __shared__ short As[2][2048];
    __shared__ short Bs[2][2048];

    int bid = blockIdx.x;
    int swz = (bid & 7) * 96 + (bid >> 3);   // 768 % 8 == 0 -> bijective
    int mb = swz / 12;
    int nb = swz - mb * 12;

    int tid  = threadIdx.x;
    int lane = tid & 63;
    int w    = tid >> 6;      // wave 0..3
    int wr   = w >> 1;        // wave row (32 m)
    int wc   = w & 1;         // wave col (32 n)

    int r16 = lane & 15;
    int kp  = lane >> 4;      // 0..3 (k-chunk of 8)

    // staging source: thread t supplies LDS bytes t*16.. (fragment-major order)
    const uint16_t* aptr = wout + ((size_t)(mb * 64 + w * 16 + r16)) * KP + kp * 8;
    const uint16_t* bptr = wobt + ((size_t)(nb * 64 + w * 16 + r16)) * KP + kp * 8;

    // wave-uniform LDS staging bases (wave w covers bytes w*1024..)
    short* adst[2] = { &As[0][w * 512], &As[1][w * 512] };
    short* bdst[2] = { &Bs[0][w * 512], &Bs[1][w * 512] };

    f32x4 acc[2][2] = {};

    // prologue: stage tile 0 into buf 0
    gload_lds16(aptr, adst[0]);
    gload_lds16(bptr, bdst[0]);
    __syncthreads();

    int cur = 0;
    for (int kt = 0; kt < 129; ++kt) {
        if (kt < 128) {
            gload_lds16(aptr + (size_t)(kt + 1) * 32, adst[cur ^ 1]);
            gload_lds16(bptr + (size_t)(kt + 1) * 32, bdst[cur ^ 1]);
        }
        const short* Ab = As[cur];
        const short* Bb = Bs[cur];
        bf16x8 a0 = *(const bf16x8*)(Ab + (wr * 2 + 0) * 512 + lane * 8);
        bf16x8 a1 = *(const bf16x8*)(Ab + (wr * 2 + 1) * 512 + lane * 8);
        bf16x8 b0 = *(const bf16x8*)(Bb + (wc * 2 + 0) * 512 + lane * 8);
        bf16x8 b1 = *(const bf16x8*)(Bb + (wc * 2 + 1) * 512 + lane * 8);
        acc[0][0] = __builtin_amdgcn_mfma_f32_16x16x32_bf16(a0, b0, acc[0][0], 0, 0, 0);
        acc[0][1] = __builtin_amdgcn_mfma_f32_16x16x32_bf16(a0, b1, acc[0][1], 0, 0, 0);
        acc[1][0] = __builtin_amdgcn_mfma_f32_16x16x32_bf16(a1, b0, acc[1][0], 0, 0, 0);
        acc[1][1] = __builtin_amdgcn_mfma_f32_16x16x32_bf16(a1, b1, acc[1][1], 0, 0, 0);
        __syncthreads();   // drains vmcnt (stage kt+1 done) + all waves done reading
        cur ^= 1;
    }

    // epilogue: C/D layout col = lane&15, row = (lane>>4)*4 + reg
    int mbase = mb * 64 + wr * 32 + (lane >> 4) * 4;
    int nbase = nb * 64 + wc * 32 + (lane & 15);
#pragma unroll
    for (int fm = 0; fm < 2; ++fm)
#pragma unroll
        for (int fn = 0; fn < 2; ++fn)
#pragma unroll
            for (int r = 0; r < 4; ++r)
                out[(size_t)(mbase + fm * 16 + r) * DLLM + nbase + fn * 16] =
                    acc[fm][fn][r];
}

// ---------------------------------------------------------------------------
extern "C" void kernel_launch(void* const* d_in, const int* in_sizes, int n_in,
                              void* d_out, int out_size, void* d_ws, size_t ws_size,
                              hipStream_t stream) {
    const float* topk  = (const float*)d_in[0];  // (32,100,768)
    const float* ts    = (const float*)d_in[1];  // (64,64,128)
    const float* probs = (const float*)d_in[2];  // (64,64,32)
    const float* Wq    = (const float*)d_in[3];  // (32,128,129)
    const float* Wk    = (const float*)d_in[4];  // (32,128,769)
    const float* Wv    = (const float*)d_in[5];  // (32,128,769)
    const float* Wo    = (const float*)d_in[6];  // (32,128,768) -> [4096][768]
    const float* bo    = (const float*)d_in[7];  // (32,768)
    float* out = (float*)d_out;

    // workspace layout (bf16 / uint16): kbuf | vbuf | qbuf | wout
    // WoBT (6.34 MB) overlays qbuf space (33.5 MB) -- qbuf is dead after attn.
    uint16_t* ws   = (uint16_t*)d_ws;
    uint16_t* kbuf = ws;                           // 32*100*128   = 409600
    uint16_t* vbuf = ws + 409600;                  // 409600
    uint16_t* qbuf = ws + 819200;                  // 32*4096*128  = 16777216
    uint16_t* wout = ws + 819200 + 16777216;       // 4096*4128    = 16904192
    uint16_t* wobt = qbuf;                         // 768*4128     = 3170304 (overlay)

    kv_proj_kernel<<<3328, 256, 0, stream>>>(topk, Wk, Wv, kbuf, vbuf);
    q_proj_kernel<<<2048, 256, 0, stream>>>(ts, Wq, qbuf);
    attn_kernel<<<2048, 128, 0, stream>>>(qbuf, kbuf, vbuf, probs, wout);
    convert_wo_kernel<<<1548, 256, 0, stream>>>(Wo, bo, wobt);
    fgemm_mfma_kernel<<<768, 256, 0, stream>>>(wout, wobt, out);
}

// Round 5
// 242.488 us; speedup vs baseline: 4.1441x; 1.4110x over previous
//
#include <hip/hip_runtime.h>
#include <stdint.h>

// Dims
#define NB 64
#define NL 64
#define NC 32
#define NK 100
#define NH 8
#define DKEY 16
#define DM 128
#define NG 128       // H*DKEY
#define DLLM 768
#define KP 4128      // 4096 + 32 (probs tail) : wout row stride
#define TEMP 0.25f   // 1/sqrt(16)

typedef __attribute__((ext_vector_type(8))) short bf16x8;
typedef __attribute__((ext_vector_type(4))) short bf16x4;
typedef __attribute__((ext_vector_type(4))) float f32x4;

typedef uint32_t __attribute__((address_space(1))) gu32;
typedef uint32_t __attribute__((address_space(3))) lu32;

__device__ __forceinline__ void gload_lds16(const void* g, void* l) {
    __builtin_amdgcn_global_load_lds((const gu32*)g, (lu32*)l, 16, 0, 0);
}

// ---------- bf16 helpers ----------
__device__ __forceinline__ uint16_t f2bf(float f) {
    union { float f; uint32_t i; } x; x.f = f;
    uint32_t r = x.i + 0x7FFFu + ((x.i >> 16) & 1u);
    return (uint16_t)(r >> 16);
}
__device__ __forceinline__ uint32_t pack2(float lo, float hi) {
    return (uint32_t)f2bf(lo) | ((uint32_t)f2bf(hi) << 16);
}
__device__ __forceinline__ uint32_t cvtpk_bf16(float lo, float hi) {
    uint32_t r;
    asm("v_cvt_pk_bf16_f32 %0, %1, %2" : "=v"(r) : "v"(lo), "v"(hi));
    return r;
}

// ---------------------------------------------------------------------------
// Kernel 0: convert ts and Wq (matmul part) to bf16. Outputs live in the wout
// region (dead until attn overwrites it -- q_proj consumes them before that).
// ---------------------------------------------------------------------------
__global__ __launch_bounds__(256) void convert_in_kernel(
    const float* __restrict__ ts,
    const float* __restrict__ Wq,
    uint16_t* __restrict__ tsbf,
    uint16_t* __restrict__ wqbf)
{
    int i = blockIdx.x * 256 + threadIdx.x;
    if (i < 524288) {
        tsbf[i] = f2bf(ts[i]);
    } else {
        int j = i - 524288;
        wqbf[j] = f2bf(Wq[(j >> 7) * 129 + (j & 127)]);
    }
}

// ---------------------------------------------------------------------------
// Kernel 1: K/V projection.
// kbuf[c][112][128] row-major (rows >=100 zeroed); vbufT[c][128 g][128 k]
// transposed with k in [100,128) zeroed (PV reads k to 127).
// ---------------------------------------------------------------------------
__global__ __launch_bounds__(256) void kv_proj_kernel(
    const float* __restrict__ topk,
    const float* __restrict__ Wk,
    const float* __restrict__ Wv,
    uint16_t* __restrict__ kbuf,
    uint16_t* __restrict__ vbufT)
{
    int wt = blockIdx.x * 4 + (threadIdx.x >> 6);
    int lane = threadIdx.x & 63;
    int gt = wt & 15; wt >>= 4;
    int kt = wt & 15; wt >>= 4;
    int c  = wt & 31;
    int m  = wt >> 5;

    const float* W = (m == 0 ? Wk : Wv) + (size_t)c * (128 * 769);
    const float* T = topk + (size_t)c * (NK * DLLM);

    float acc[8][8];
#pragma unroll
    for (int i = 0; i < 8; ++i)
#pragma unroll
        for (int j = 0; j < 8; ++j) acc[i][j] = 0.0f;

    for (int dc = 0; dc < 12; ++dc) {
        int d = dc * 64 + lane;
        float a[8], w[8];
#pragma unroll
        for (int i = 0; i < 8; ++i) {
            int kk = kt * 8 + i;
            a[i] = (kk < NK) ? T[kk * DLLM + d] : 0.0f;
        }
#pragma unroll
        for (int j = 0; j < 8; ++j)
            w[j] = W[(gt * 8 + j) * 769 + d];
#pragma unroll
        for (int i = 0; i < 8; ++i)
#pragma unroll
            for (int j = 0; j < 8; ++j)
                acc[i][j] = fmaf(a[i], w[j], acc[i][j]);
    }

    float res = 0.0f;
#pragma unroll
    for (int i = 0; i < 8; ++i)
#pragma unroll
        for (int j = 0; j < 8; ++j) {
            float s = acc[i][j];
            s += __shfl_xor(s, 32);
            s += __shfl_xor(s, 16);
            s += __shfl_xor(s, 8);
            s += __shfl_xor(s, 4);
            s += __shfl_xor(s, 2);
            s += __shfl_xor(s, 1);
            if (lane == i * 8 + j) res = s;
        }

    int kk = kt * 8 + (lane >> 3);
    int gg = gt * 8 + (lane & 7);
    float bias = W[gg * 769 + 768];
    uint16_t val = (kk < NK) ? f2bf(res + bias) : (uint16_t)0;
    if (m == 0) {
        if (kk < 112) kbuf[((size_t)c * 112 + kk) * 128 + gg] = val;
    } else {
        vbufT[((size_t)c * 128 + gg) * 128 + kk] = val;
    }
}

// ---------------------------------------------------------------------------
// Kernel 2: Q projection via MFMA. qbuf[c][4096][128] bf16 =
// tsbf[4096][128] @ wqbf[c]^T + bias. 64x64 tile, 4 waves 2x2 frag, K=128.
// ---------------------------------------------------------------------------
__global__ __launch_bounds__(256) void q_proj_mfma_kernel(
    const uint16_t* __restrict__ tsbf,   // [4096][128]
    const uint16_t* __restrict__ wqbf,   // [32][128][128]
    const float* __restrict__ Wq,        // bias col
    uint16_t* __restrict__ qbuf)
{
    __shared__ short As[2][2048];
    __shared__ short Bs[2][2048];

    int bid = blockIdx.x;
    int mb = bid & 63;
    int nb = (bid >> 6) & 1;
    int c  = bid >> 7;

    int tid  = threadIdx.x;
    int lane = tid & 63;
    int w    = tid >> 6;
    int wr   = w >> 1;
    int wc   = w & 1;

    int r16 = lane & 15;
    int kp  = lane >> 4;

    const uint16_t* aptr = tsbf + ((size_t)(mb * 64 + w * 16 + r16)) * 128 + kp * 8;
    const uint16_t* bptr = wqbf + ((size_t)(c * 128 + nb * 64 + w * 16 + r16)) * 128 + kp * 8;

    short* adst[2] = { &As[0][w * 512], &As[1][w * 512] };
    short* bdst[2] = { &Bs[0][w * 512], &Bs[1][w * 512] };

    f32x4 acc[2][2] = {};

    gload_lds16(aptr, adst[0]);
    gload_lds16(bptr, bdst[0]);
    __syncthreads();

    int cur = 0;
    for (int kt = 0; kt < 4; ++kt) {
        if (kt < 3) {
            gload_lds16(aptr + (kt + 1) * 32, adst[cur ^ 1]);
            gload_lds16(bptr + (kt + 1) * 32, bdst[cur ^ 1]);
        }
        const short* Ab = As[cur];
        const short* Bb = Bs[cur];
        bf16x8 a0 = *(const bf16x8*)(Ab + (wr * 2 + 0) * 512 + lane * 8);
        bf16x8 a1 = *(const bf16x8*)(Ab + (wr * 2 + 1) * 512 + lane * 8);
        bf16x8 b0 = *(const bf16x8*)(Bb + (wc * 2 + 0) * 512 + lane * 8);
        bf16x8 b1 = *(const bf16x8*)(Bb + (wc * 2 + 1) * 512 + lane * 8);
        acc[0][0] = __builtin_amdgcn_mfma_f32_16x16x32_bf16(a0, b0, acc[0][0], 0, 0, 0);
        acc[0][1] = __builtin_amdgcn_mfma_f32_16x16x32_bf16(a0, b1, acc[0][1], 0, 0, 0);
        acc[1][0] = __builtin_amdgcn_mfma_f32_16x16x32_bf16(a1, b0, acc[1][0], 0, 0, 0);
        acc[1][1] = __builtin_amdgcn_mfma_f32_16x16x32_bf16(a1, b1, acc[1][1], 0, 0, 0);
        __syncthreads();
        cur ^= 1;
    }

    int mbase = mb * 64 + wr * 32 + (lane >> 4) * 4;
    int nbase = nb * 64 + wc * 32 + (lane & 15);
#pragma unroll
    for (int fn = 0; fn < 2; ++fn) {
        int ncol = nbase + fn * 16;
        float bias = Wq[((size_t)c * 128 + ncol) * 129 + 128];
#pragma unroll
        for (int fm = 0; fm < 2; ++fm)
#pragma unroll
            for (int r = 0; r < 4; ++r)
                qbuf[((size_t)c * 4096 + mbase + fm * 16 + r) * 128 + ncol] =
                    f2bf(acc[fm][fn][r] + bias);
    }
}

// ---------------------------------------------------------------------------
// Kernel 3: MFMA attention. Block = (b,c), 4 waves x 2 heads.
// FIX vs round 4: static LDS was 66,816 B (> 64 KiB sharedMemPerBlock) -->
// launch silently failed, wout stayed uninitialized, fgemm amplified garbage.
// Now LDS = Pl only = exactly 65,536 B; probs and 1/sum live in registers and
// are fetched in the epilogue via __shfl.
// ---------------------------------------------------------------------------
__global__ __launch_bounds__(256) void attn_mfma_kernel(
    const uint16_t* __restrict__ qbuf,
    const uint16_t* __restrict__ kbuf,
    const uint16_t* __restrict__ vbufT,
    const float* __restrict__ probs,
    uint16_t* __restrict__ wout)
{
    __shared__ short Pl[4][64][128];   // 65536 B == 64 KiB exactly

    int bid = blockIdx.x;
    int c = bid >> 6;
    int b = bid & 63;
    int tid = threadIdx.x;
    int lane = tid & 63;
    int w = tid >> 6;
    int g = lane >> 4;        // 0..3
    int l15 = lane & 15;
    int swz = l15 << 4;       // 16B-block XOR swizzle key

    // per-lane prob for token = lane (each wave loads the same 64 values)
    float pr_tok = probs[((size_t)b * 64 + lane) * NC + c];

    uint8_t* Pb = (uint8_t*)&Pl[w][0][0];
    bf16x8 zf = {};

    for (int hh = 0; hh < 2; ++hh) {
        int h = w * 2 + hh;

        // Q fragments (B-operand): groups 0,1 real (d 0..15), groups 2,3 zero
        bf16x8 qb[4];
#pragma unroll
        for (int nt = 0; nt < 4; ++nt) {
            if (g < 2)
                qb[nt] = *(const bf16x8*)&qbuf[((size_t)c * 4096 + b * 64 + nt * 16 + l15) * 128 + h * 16 + g * 8];
            else
                qb[nt] = zf;
        }

        float psum[4] = {0.f, 0.f, 0.f, 0.f};
#pragma unroll
        for (int mt = 0; mt < 7; ++mt) {
            bf16x8 ka;
            if (g < 2)
                ka = *(const bf16x8*)&kbuf[((size_t)c * 112 + mt * 16 + l15) * 128 + h * 16 + g * 8];
            else
                ka = zf;
            f32x4 s[4];
#pragma unroll
            for (int nt = 0; nt < 4; ++nt)
                s[nt] = __builtin_amdgcn_mfma_f32_16x16x32_bf16(ka, qb[nt], (f32x4){0.f,0.f,0.f,0.f}, 0, 0, 0);
            // rows k = mt*16 + 4g + r ; valid iff k < 100
            bool valid = (mt < 6) || (g == 0);
#pragma unroll
            for (int nt = 0; nt < 4; ++nt) {
                float p0 = valid ? __expf(s[nt][0] * TEMP) : 0.f;
                float p1 = valid ? __expf(s[nt][1] * TEMP) : 0.f;
                float p2 = valid ? __expf(s[nt][2] * TEMP) : 0.f;
                float p3 = valid ? __expf(s[nt][3] * TEMP) : 0.f;
                psum[nt] += (p0 + p1) + (p2 + p3);
                union { uint32_t u[2]; bf16x4 v; } pk;
                pk.u[0] = cvtpk_bf16(p0, p1);
                pk.u[1] = cvtpk_bf16(p2, p3);
                int l = nt * 16 + l15;
                *(bf16x4*)(Pb + l * 256 + ((mt * 32 + g * 8) ^ swz)) = pk.v;
            }
        }
        // zero pad P cols 112..127
        {
            bf16x4 z4 = {};
#pragma unroll
            for (int nt = 0; nt < 4; ++nt) {
                int l = nt * 16 + l15;
                *(bf16x4*)(Pb + l * 256 + ((224 + g * 8) ^ swz)) = z4;
            }
        }
        // fence: all P ds_writes visible before PV ds_reads
        __syncthreads();

        // full softmax denominators -> registers (every lane gets all copies)
        float rsum[4];
#pragma unroll
        for (int nt = 0; nt < 4; ++nt) {
            float t = psum[nt];
            t += __shfl_xor(t, 16);
            t += __shfl_xor(t, 32);
            rsum[nt] = __builtin_amdgcn_rcpf(t);   // 1/sum for token nt*16+l15
        }

        // PV: oacc[l-tile] over 4 k-chunks of 32
        f32x4 oacc[4] = {};
#pragma unroll
        for (int ch = 0; ch < 4; ++ch) {
            bf16x8 vb = *(const bf16x8*)&vbufT[((size_t)c * 128 + h * 16 + l15) * 128 + ch * 32 + g * 8];
#pragma unroll
            for (int mt = 0; mt < 4; ++mt) {
                int l = mt * 16 + l15;
                bf16x8 pa = *(const bf16x8*)(Pb + l * 256 + ((ch * 64 + g * 16) ^ swz));
                oacc[mt] = __builtin_amdgcn_mfma_f32_16x16x32_bf16(pa, vb, oacc[mt], 0, 0, 0);
            }
        }
        // epilogue: out[l][d], col d = lane&15, row l = mt*16 + 4g + r
        // sc for token l fetched via shfl: pr from lane l, 1/sum from lane 4g+r
#pragma unroll
        for (int mt = 0; mt < 4; ++mt) {
#pragma unroll
            for (int r = 0; r < 4; ++r) {
                int l = mt * 16 + g * 4 + r;
                float sc = __shfl(pr_tok, l) * __shfl(rsum[mt], g * 4 + r);
                wout[((size_t)b * 64 + l) * KP + c * 128 + h * 16 + l15] =
                    f2bf(oacc[mt][r] * sc);
            }
        }
        // fence: PV ds_reads done before next head's P ds_writes (WAR)
        __syncthreads();
    }
    // probs tail column
    if (tid < 64)
        wout[((size_t)b * 64 + tid) * KP + 4096 + c] = f2bf(pr_tok);
}

// ---------------------------------------------------------------------------
// Kernel 4a: transpose+convert [Wo;bo] fp32 [4128][768] -> WoBT bf16 [768][4128]
// ---------------------------------------------------------------------------
__global__ __launch_bounds__(256) void convert_wo_kernel(
    const float* __restrict__ Wo,
    const float* __restrict__ bo,
    uint16_t* __restrict__ wobt)
{
    __shared__ float tile[32][65];
    int bid = blockIdx.x;
    int kt = bid / 12;
    int nb = bid % 12;
    int t = threadIdx.x;
    {
        int rr = t >> 3;
        int c0 = (t & 7) * 8;
        int kg = kt * 32 + rr;
        const float* src = (kg < 4096 ? Wo + (size_t)kg * DLLM
                                      : bo + (size_t)(kg - 4096) * DLLM)
                           + nb * 64 + c0;
        float4 v0 = *(const float4*)src;
        float4 v1 = *(const float4*)(src + 4);
        tile[rr][c0 + 0] = v0.x; tile[rr][c0 + 1] = v0.y;
        tile[rr][c0 + 2] = v0.z; tile[rr][c0 + 3] = v0.w;
        tile[rr][c0 + 4] = v1.x; tile[rr][c0 + 5] = v1.y;
        tile[rr][c0 + 6] = v1.z; tile[rr][c0 + 7] = v1.w;
    }
    __syncthreads();
    {
        int n  = t >> 2;
        int k0 = (t & 3) * 8;
        uint4 u;
        u.x = pack2(tile[k0 + 0][n], tile[k0 + 1][n]);
        u.y = pack2(tile[k0 + 2][n], tile[k0 + 3][n]);
        u.z = pack2(tile[k0 + 4][n], tile[k0 + 5][n]);
        u.w = pack2(tile[k0 + 6][n], tile[k0 + 7][n]);
        *(uint4*)&wobt[((size_t)(nb * 64 + n)) * KP + kt * 32 + k0] = u;
    }
}

// ---------------------------------------------------------------------------
// Kernel 4b: MFMA GEMM. out[4096,768] = wout(bf16)[4096,4128] @ WoBT^T
// ---------------------------------------------------------------------------
__global__ __launch_bounds__(256) void fgemm_mfma_kernel(
    const uint16_t* __restrict__ wout,   // A  [4096][4128] bf16
    const uint16_t* __restrict__ wobt,   // B^T [768][4128] bf16
    float* __restrict__ out)             // [4096][768] fp32
{
    __shared__ short As[2][2048];
    __shared__ short Bs[2][2048];

    int bid = blockIdx.x;
    int swz = (bid & 7) * 96 + (bid >> 3);
    int mb = swz / 12;
    int nb = swz - mb * 12;

    int tid  = threadIdx.x;
    int lane = tid & 63;
    int w    = tid >> 6;
    int wr   = w >> 1;
    int wc   = w & 1;

    int r16 = lane & 15;
    int kp  = lane >> 4;

    const uint16_t* aptr = wout + ((size_t)(mb * 64 + w * 16 + r16)) * KP + kp * 8;
    const uint16_t* bptr = wobt + ((size_t)(nb * 64 + w * 16 + r16)) * KP + kp * 8;

    short* adst[2] = { &As[0][w * 512], &As[1][w * 512] };
    short* bdst[2] = { &Bs[0][w * 512], &Bs[1][w * 512] };

    f32x4 acc[2][2] = {};

    gload_lds16(aptr, adst[0]);
    gload_lds16(bptr, bdst[0]);
    __syncthreads();

    int cur = 0;
    for (int kt = 0; kt < 129; ++kt) {
        if (kt < 128) {
            gload_lds16(aptr + (size_t)(kt + 1) * 32, adst[cur ^ 1]);
            gload_lds16(bptr + (size_t)(kt + 1) * 32, bdst[cur ^ 1]);
        }
        const short* Ab = As[cur];
        const short* Bb = Bs[cur];
        bf16x8 a0 = *(const bf16x8*)(Ab + (wr * 2 + 0) * 512 + lane * 8);
        bf16x8 a1 = *(const bf16x8*)(Ab + (wr * 2 + 1) * 512 + lane * 8);
        bf16x8 b0 = *(const bf16x8*)(Bb + (wc * 2 + 0) * 512 + lane * 8);
        bf16x8 b1 = *(const bf16x8*)(Bb + (wc * 2 + 1) * 512 + lane * 8);
        acc[0][0] = __builtin_amdgcn_mfma_f32_16x16x32_bf16(a0, b0, acc[0][0], 0, 0, 0);
        acc[0][1] = __builtin_amdgcn_mfma_f32_16x16x32_bf16(a0, b1, acc[0][1], 0, 0, 0);
        acc[1][0] = __builtin_amdgcn_mfma_f32_16x16x32_bf16(a1, b0, acc[1][0], 0, 0, 0);
        acc[1][1] = __builtin_amdgcn_mfma_f32_16x16x32_bf16(a1, b1, acc[1][1], 0, 0, 0);
        __syncthreads();
        cur ^= 1;
    }

    int mbase = mb * 64 + wr * 32 + (lane >> 4) * 4;
    int nbase = nb * 64 + wc * 32 + (lane & 15);
#pragma unroll
    for (int fm = 0; fm < 2; ++fm)
#pragma unroll
        for (int fn = 0; fn < 2; ++fn)
#pragma unroll
            for (int r = 0; r < 4; ++r)
                out[(size_t)(mbase + fm * 16 + r) * DLLM + nbase + fn * 16] =
                    acc[fm][fn][r];
}

// ---------------------------------------------------------------------------
extern "C" void kernel_launch(void* const* d_in, const int* in_sizes, int n_in,
                              void* d_out, int out_size, void* d_ws, size_t ws_size,
                              hipStream_t stream) {
    const float* topk  = (const float*)d_in[0];  // (32,100,768)
    const float* ts    = (const float*)d_in[1];  // (64,64,128)
    const float* probs = (const float*)d_in[2];  // (64,64,32)
    const float* Wq    = (const float*)d_in[3];  // (32,128,129)
    const float* Wk    = (const float*)d_in[4];  // (32,128,769)
    const float* Wv    = (const float*)d_in[5];  // (32,128,769)
    const float* Wo    = (const float*)d_in[6];  // (32,128,768)
    const float* bo    = (const float*)d_in[7];  // (32,768)
    float* out = (float*)d_out;

    // workspace (uint16): kbuf | vbufT | qbuf | wout   (~69.3 MB)
    uint16_t* ws    = (uint16_t*)d_ws;
    uint16_t* kbuf  = ws;                          // 32*112*128 = 458752
    uint16_t* vbufT = ws + 458752;                 // 32*128*128 = 524288
    uint16_t* qbuf  = ws + 983040;                 // 32*4096*128 = 16777216
    uint16_t* wout  = ws + 983040 + 16777216;      // 4096*4128 = 16908288
    // overlays (regions dead during their use):
    uint16_t* wobt = qbuf;                         // 768*4128 after attn
    uint16_t* tsbf = wout;                         // 524288, dead after q_proj
    uint16_t* wqbf = wout + 524288;                // 524288, dead after q_proj

    convert_in_kernel<<<4096, 256, 0, stream>>>(ts, Wq, tsbf, wqbf);
    kv_proj_kernel<<<4096, 256, 0, stream>>>(topk, Wk, Wv, kbuf, vbufT);
    q_proj_mfma_kernel<<<4096, 256, 0, stream>>>(tsbf, wqbf, Wq, qbuf);
    attn_mfma_kernel<<<2048, 256, 0, stream>>>(qbuf, kbuf, vbufT, probs, wout);
    convert_wo_kernel<<<1548, 256, 0, stream>>>(Wo, bo, wobt);
    fgemm_mfma_kernel<<<768, 256, 0, stream>>>(wout, wobt, out);
}

// Round 6
// 191.963 us; speedup vs baseline: 5.2348x; 1.2632x over previous
//
#include <hip/hip_runtime.h>
#include <stdint.h>

// Dims
#define NB 64
#define NL 64
#define NC 32
#define NK 100
#define NH 8
#define DKEY 16
#define DM 128
#define NG 128       // H*DKEY
#define DLLM 768
#define KP 4128      // 4096 + 32 (probs tail) : wout row stride
#define TEMP 0.25f   // 1/sqrt(16)

typedef __attribute__((ext_vector_type(8))) short bf16x8;
typedef __attribute__((ext_vector_type(4))) short bf16x4;
typedef __attribute__((ext_vector_type(4))) float f32x4;

typedef uint32_t __attribute__((address_space(1))) gu32;
typedef uint32_t __attribute__((address_space(3))) lu32;

__device__ __forceinline__ void gload_lds16(const void* g, void* l) {
    __builtin_amdgcn_global_load_lds((const gu32*)g, (lu32*)l, 16, 0, 0);
}

// ---------- bf16 helpers ----------
__device__ __forceinline__ uint16_t f2bf(float f) {
    union { float f; uint32_t i; } x; x.f = f;
    uint32_t r = x.i + 0x7FFFu + ((x.i >> 16) & 1u);
    return (uint16_t)(r >> 16);
}
__device__ __forceinline__ uint32_t pack2(float lo, float hi) {
    return (uint32_t)f2bf(lo) | ((uint32_t)f2bf(hi) << 16);
}
__device__ __forceinline__ uint32_t cvtpk_bf16(float lo, float hi) {
    uint32_t r;
    asm("v_cvt_pk_bf16_f32 %0, %1, %2" : "=v"(r) : "v"(lo), "v"(hi));
    return r;
}

// ---------------------------------------------------------------------------
// Kernel 0: convert ts and Wq (matmul part) to bf16. Outputs live in the wout
// region (dead until attn overwrites it -- q_proj consumes them before that).
// ---------------------------------------------------------------------------
__global__ __launch_bounds__(256) void convert_in_kernel(
    const float* __restrict__ ts,
    const float* __restrict__ Wq,
    uint16_t* __restrict__ tsbf,
    uint16_t* __restrict__ wqbf)
{
    int i = blockIdx.x * 256 + threadIdx.x;
    if (i < 524288) {
        tsbf[i] = f2bf(ts[i]);
    } else {
        int j = i - 524288;
        wqbf[j] = f2bf(Wq[(j >> 7) * 129 + (j & 127)]);
    }
}

// ---------------------------------------------------------------------------
// Kernel 0b: convert topk / Wk / Wv (matmul parts) to bf16.
// One row of 768 per block. topk rows are 16B-aligned -> float4 path;
// W rows start at odd*769 fp32 offsets -> scalar coalesced path.
// grid = 3200 + 4096 + 4096 = 11392.
// ---------------------------------------------------------------------------
__global__ __launch_bounds__(256) void convert_kv_kernel(
    const float* __restrict__ topk,
    const float* __restrict__ Wk,
    const float* __restrict__ Wv,
    uint16_t* __restrict__ topkbf,
    uint16_t* __restrict__ wkbf,
    uint16_t* __restrict__ wvbf)
{
    int r = blockIdx.x;
    int t = threadIdx.x;
    if (r < 3200) {
        if (t < 192) {
            float4 v = *(const float4*)(topk + (size_t)r * 768 + t * 4);
            uint2 u;
            u.x = pack2(v.x, v.y);
            u.y = pack2(v.z, v.w);
            *(uint2*)(topkbf + (size_t)r * 768 + t * 4) = u;
        }
    } else {
        int rr = r - 3200;
        const float* src;
        uint16_t* dst;
        if (rr < 4096) {
            src = Wk + (size_t)rr * 769;
            dst = wkbf + (size_t)rr * 768;
        } else {
            rr -= 4096;
            src = Wv + (size_t)rr * 769;
            dst = wvbf + (size_t)rr * 768;
        }
#pragma unroll
        for (int i = 0; i < 3; ++i)
            dst[t + 256 * i] = f2bf(src[t + 256 * i]);
    }
}

// ---------------------------------------------------------------------------
// Kernel 1: K/V projection via MFMA (replaces the fp32 wave-dot kernel).
// which==0 (K): out[kk][g] = topk[kk,:]*Wk[g,:] + bias(g) -> kbuf[c][112][128]
//               (rows >=112 skipped; rows 100..111 garbage-but-finite, masked
//                downstream in attn exactly as before)
// which==1 (V): out computed TRANSPOSED: vT[g][kk] = topk[kk,:]*Wv[g,:]+bias(g)
//               -> vbufT[c][128][128], cols kk>=100 forced to 0 (PV invariant).
// A/B pad rows beyond topk's 100 rows read adjacent converted bf16 buffers:
// finite garbage, never unmasked. 64x64 tile, 4 waves 2x2 frag, K=768 (24 steps).
// grid = 2*32*2*2 = 256 blocks.
// ---------------------------------------------------------------------------
__global__ __launch_bounds__(256) void kv_mfma_kernel(
    const uint16_t* __restrict__ topkbf,  // [3200][768]
    const uint16_t* __restrict__ wkbf,    // [32*128][768]
    const uint16_t* __restrict__ wvbf,    // [32*128][768]
    const float* __restrict__ Wk,         // bias col
    const float* __restrict__ Wv,         // bias col
    uint16_t* __restrict__ kbuf,          // [32][112][128]
    uint16_t* __restrict__ vbufT)         // [32][128][128]
{
    __shared__ short As[2][2048];
    __shared__ short Bs[2][2048];

    int bid = blockIdx.x;
    int nb = bid & 1;
    int mb = (bid >> 1) & 1;
    int c  = (bid >> 2) & 31;
    int which = bid >> 7;     // 0=K, 1=V

    int tid  = threadIdx.x;
    int lane = tid & 63;
    int w    = tid >> 6;
    int wr   = w >> 1;
    int wc   = w & 1;
    int r16  = lane & 15;
    int kp   = lane >> 4;

    int arow = mb * 64 + w * 16 + r16;
    int brow = nb * 64 + w * 16 + r16;
    const uint16_t* aptr;
    const uint16_t* bptr;
    if (which == 0) {
        aptr = topkbf + ((size_t)(c * 100 + arow)) * 768 + kp * 8;
        bptr = wkbf   + ((size_t)(c * 128 + brow)) * 768 + kp * 8;
    } else {
        aptr = wvbf   + ((size_t)(c * 128 + arow)) * 768 + kp * 8;
        bptr = topkbf + ((size_t)(c * 100 + brow)) * 768 + kp * 8;
    }

    short* adst[2] = { &As[0][w * 512], &As[1][w * 512] };
    short* bdst[2] = { &Bs[0][w * 512], &Bs[1][w * 512] };

    f32x4 acc[2][2] = {};

    gload_lds16(aptr, adst[0]);
    gload_lds16(bptr, bdst[0]);
    __syncthreads();

    int cur = 0;
    for (int kt = 0; kt < 24; ++kt) {
        if (kt < 23) {
            gload_lds16(aptr + (kt + 1) * 32, adst[cur ^ 1]);
            gload_lds16(bptr + (kt + 1) * 32, bdst[cur ^ 1]);
        }
        const short* Ab = As[cur];
        const short* Bb = Bs[cur];
        bf16x8 a0 = *(const bf16x8*)(Ab + (wr * 2 + 0) * 512 + lane * 8);
        bf16x8 a1 = *(const bf16x8*)(Ab + (wr * 2 + 1) * 512 + lane * 8);
        bf16x8 b0 = *(const bf16x8*)(Bb + (wc * 2 + 0) * 512 + lane * 8);
        bf16x8 b1 = *(const bf16x8*)(Bb + (wc * 2 + 1) * 512 + lane * 8);
        acc[0][0] = __builtin_amdgcn_mfma_f32_16x16x32_bf16(a0, b0, acc[0][0], 0, 0, 0);
        acc[0][1] = __builtin_amdgcn_mfma_f32_16x16x32_bf16(a0, b1, acc[0][1], 0, 0, 0);
        acc[1][0] = __builtin_amdgcn_mfma_f32_16x16x32_bf16(a1, b0, acc[1][0], 0, 0, 0);
        acc[1][1] = __builtin_amdgcn_mfma_f32_16x16x32_bf16(a1, b1, acc[1][1], 0, 0, 0);
        __syncthreads();
        cur ^= 1;
    }

    int mbase = mb * 64 + wr * 32 + (lane >> 4) * 4;
    int nbase = nb * 64 + wc * 32 + (lane & 15);

    if (which == 0) {
        // K: row = token kk, col = g; bias per col
        float bias0 = Wk[((size_t)c * 128 + nbase)      * 769 + 768];
        float bias1 = Wk[((size_t)c * 128 + nbase + 16) * 769 + 768];
#pragma unroll
        for (int fm = 0; fm < 2; ++fm)
#pragma unroll
            for (int r = 0; r < 4; ++r) {
                int mrow = mbase + fm * 16 + r;
                if (mrow < 112) {
                    kbuf[((size_t)c * 112 + mrow) * 128 + nbase]      = f2bf(acc[fm][0][r] + bias0);
                    kbuf[((size_t)c * 112 + mrow) * 128 + nbase + 16] = f2bf(acc[fm][1][r] + bias1);
                }
            }
    } else {
        // V^T: row = g, col = token kk; bias per row; cols >= 100 -> 0
#pragma unroll
        for (int fm = 0; fm < 2; ++fm)
#pragma unroll
            for (int r = 0; r < 4; ++r) {
                int grow = mbase + fm * 16 + r;
                float bias = Wv[((size_t)c * 128 + grow) * 769 + 768];
#pragma unroll
                for (int fn = 0; fn < 2; ++fn) {
                    int ncol = nbase + fn * 16;
                    uint16_t val = (ncol < NK) ? f2bf(acc[fm][fn][r] + bias) : (uint16_t)0;
                    vbufT[((size_t)c * 128 + grow) * 128 + ncol] = val;
                }
            }
    }
}

// ---------------------------------------------------------------------------
// Kernel 2: Q projection via MFMA. qbuf[c][4096][128] bf16 =
// tsbf[4096][128] @ wqbf[c]^T + bias. 64x64 tile, 4 waves 2x2 frag, K=128.
// ---------------------------------------------------------------------------
__global__ __launch_bounds__(256) void q_proj_mfma_kernel(
    const uint16_t* __restrict__ tsbf,   // [4096][128]
    const uint16_t* __restrict__ wqbf,   // [32][128][128]
    const float* __restrict__ Wq,        // bias col
    uint16_t* __restrict__ qbuf)
{
    __shared__ short As[2][2048];
    __shared__ short Bs[2][2048];

    int bid = blockIdx.x;
    int mb = bid & 63;
    int nb = (bid >> 6) & 1;
    int c  = bid >> 7;

    int tid  = threadIdx.x;
    int lane = tid & 63;
    int w    = tid >> 6;
    int wr   = w >> 1;
    int wc   = w & 1;

    int r16 = lane & 15;
    int kp  = lane >> 4;

    const uint16_t* aptr = tsbf + ((size_t)(mb * 64 + w * 16 + r16)) * 128 + kp * 8;
    const uint16_t* bptr = wqbf + ((size_t)(c * 128 + nb * 64 + w * 16 + r16)) * 128 + kp * 8;

    short* adst[2] = { &As[0][w * 512], &As[1][w * 512] };
    short* bdst[2] = { &Bs[0][w * 512], &Bs[1][w * 512] };

    f32x4 acc[2][2] = {};

    gload_lds16(aptr, adst[0]);
    gload_lds16(bptr, bdst[0]);
    __syncthreads();

    int cur = 0;
    for (int kt = 0; kt < 4; ++kt) {
        if (kt < 3) {
            gload_lds16(aptr + (kt + 1) * 32, adst[cur ^ 1]);
            gload_lds16(bptr + (kt + 1) * 32, bdst[cur ^ 1]);
        }
        const short* Ab = As[cur];
        const short* Bb = Bs[cur];
        bf16x8 a0 = *(const bf16x8*)(Ab + (wr * 2 + 0) * 512 + lane * 8);
        bf16x8 a1 = *(const bf16x8*)(Ab + (wr * 2 + 1) * 512 + lane * 8);
        bf16x8 b0 = *(const bf16x8*)(Bb + (wc * 2 + 0) * 512 + lane * 8);
        bf16x8 b1 = *(const bf16x8*)(Bb + (wc * 2 + 1) * 512 + lane * 8);
        acc[0][0] = __builtin_amdgcn_mfma_f32_16x16x32_bf16(a0, b0, acc[0][0], 0, 0, 0);
        acc[0][1] = __builtin_amdgcn_mfma_f32_16x16x32_bf16(a0, b1, acc[0][1], 0, 0, 0);
        acc[1][0] = __builtin_amdgcn_mfma_f32_16x16x32_bf16(a1, b0, acc[1][0], 0, 0, 0);
        acc[1][1] = __builtin_amdgcn_mfma_f32_16x16x32_bf16(a1, b1, acc[1][1], 0, 0, 0);
        __syncthreads();
        cur ^= 1;
    }

    int mbase = mb * 64 + wr * 32 + (lane >> 4) * 4;
    int nbase = nb * 64 + wc * 32 + (lane & 15);
#pragma unroll
    for (int fn = 0; fn < 2; ++fn) {
        int ncol = nbase + fn * 16;
        float bias = Wq[((size_t)c * 128 + ncol) * 129 + 128];
#pragma unroll
        for (int fm = 0; fm < 2; ++fm)
#pragma unroll
            for (int r = 0; r < 4; ++r)
                qbuf[((size_t)c * 4096 + mbase + fm * 16 + r) * 128 + ncol] =
                    f2bf(acc[fm][fn][r] + bias);
    }
}

// ---------------------------------------------------------------------------
// Kernel 3: MFMA attention. Block = (b,c), 4 waves x 2 heads.
// LDS = Pl only = exactly 65,536 B (64 KiB limit); probs and 1/sum live in
// registers, fetched in the epilogue via __shfl.
// ---------------------------------------------------------------------------
__global__ __launch_bounds__(256) void attn_mfma_kernel(
    const uint16_t* __restrict__ qbuf,
    const uint16_t* __restrict__ kbuf,
    const uint16_t* __restrict__ vbufT,
    const float* __restrict__ probs,
    uint16_t* __restrict__ wout)
{
    __shared__ short Pl[4][64][128];   // 65536 B == 64 KiB exactly

    int bid = blockIdx.x;
    int c = bid >> 6;
    int b = bid & 63;
    int tid = threadIdx.x;
    int lane = tid & 63;
    int w = tid >> 6;
    int g = lane >> 4;        // 0..3
    int l15 = lane & 15;
    int swz = l15 << 4;       // 16B-block XOR swizzle key

    // per-lane prob for token = lane (each wave loads the same 64 values)
    float pr_tok = probs[((size_t)b * 64 + lane) * NC + c];

    uint8_t* Pb = (uint8_t*)&Pl[w][0][0];
    bf16x8 zf = {};

    for (int hh = 0; hh < 2; ++hh) {
        int h = w * 2 + hh;

        // Q fragments (B-operand): groups 0,1 real (d 0..15), groups 2,3 zero
        bf16x8 qb[4];
#pragma unroll
        for (int nt = 0; nt < 4; ++nt) {
            if (g < 2)
                qb[nt] = *(const bf16x8*)&qbuf[((size_t)c * 4096 + b * 64 + nt * 16 + l15) * 128 + h * 16 + g * 8];
            else
                qb[nt] = zf;
        }

        float psum[4] = {0.f, 0.f, 0.f, 0.f};
#pragma unroll
        for (int mt = 0; mt < 7; ++mt) {
            bf16x8 ka;
            if (g < 2)
                ka = *(const bf16x8*)&kbuf[((size_t)c * 112 + mt * 16 + l15) * 128 + h * 16 + g * 8];
            else
                ka = zf;
            f32x4 s[4];
#pragma unroll
            for (int nt = 0; nt < 4; ++nt)
                s[nt] = __builtin_amdgcn_mfma_f32_16x16x32_bf16(ka, qb[nt], (f32x4){0.f,0.f,0.f,0.f}, 0, 0, 0);
            // rows k = mt*16 + 4g + r ; valid iff k < 100
            bool valid = (mt < 6) || (g == 0);
#pragma unroll
            for (int nt = 0; nt < 4; ++nt) {
                float p0 = valid ? __expf(s[nt][0] * TEMP) : 0.f;
                float p1 = valid ? __expf(s[nt][1] * TEMP) : 0.f;
                float p2 = valid ? __expf(s[nt][2] * TEMP) : 0.f;
                float p3 = valid ? __expf(s[nt][3] * TEMP) : 0.f;
                psum[nt] += (p0 + p1) + (p2 + p3);
                union { uint32_t u[2]; bf16x4 v; } pk;
                pk.u[0] = cvtpk_bf16(p0, p1);
                pk.u[1] = cvtpk_bf16(p2, p3);
                int l = nt * 16 + l15;
                *(bf16x4*)(Pb + l * 256 + ((mt * 32 + g * 8) ^ swz)) = pk.v;
            }
        }
        // zero pad P cols 112..127
        {
            bf16x4 z4 = {};
#pragma unroll
            for (int nt = 0; nt < 4; ++nt) {
                int l = nt * 16 + l15;
                *(bf16x4*)(Pb + l * 256 + ((224 + g * 8) ^ swz)) = z4;
            }
        }
        // fence: all P ds_writes visible before PV ds_reads
        __syncthreads();

        // full softmax denominators -> registers (every lane gets all copies)
        float rsum[4];
#pragma unroll
        for (int nt = 0; nt < 4; ++nt) {
            float t = psum[nt];
            t += __shfl_xor(t, 16);
            t += __shfl_xor(t, 32);
            rsum[nt] = __builtin_amdgcn_rcpf(t);   // 1/sum for token nt*16+l15
        }

        // PV: oacc[l-tile] over 4 k-chunks of 32
        f32x4 oacc[4] = {};
#pragma unroll
        for (int ch = 0; ch < 4; ++ch) {
            bf16x8 vb = *(const bf16x8*)&vbufT[((size_t)c * 128 + h * 16 + l15) * 128 + ch * 32 + g * 8];
#pragma unroll
            for (int mt = 0; mt < 4; ++mt) {
                int l = mt * 16 + l15;
                bf16x8 pa = *(const bf16x8*)(Pb + l * 256 + ((ch * 64 + g * 16) ^ swz));
                oacc[mt] = __builtin_amdgcn_mfma_f32_16x16x32_bf16(pa, vb, oacc[mt], 0, 0, 0);
            }
        }
        // epilogue: out[l][d], col d = lane&15, row l = mt*16 + 4g + r
#pragma unroll
        for (int mt = 0; mt < 4; ++mt) {
#pragma unroll
            for (int r = 0; r < 4; ++r) {
                int l = mt * 16 + g * 4 + r;
                float sc = __shfl(pr_tok, l) * __shfl(rsum[mt], g * 4 + r);
                wout[((size_t)b * 64 + l) * KP + c * 128 + h * 16 + l15] =
                    f2bf(oacc[mt][r] * sc);
            }
        }
        // fence: PV ds_reads done before next head's P ds_writes (WAR)
        __syncthreads();
    }
    // probs tail column
    if (tid < 64)
        wout[((size_t)b * 64 + tid) * KP + 4096 + c] = f2bf(pr_tok);
}

// ---------------------------------------------------------------------------
// Kernel 4a: transpose+convert [Wo;bo] fp32 [4128][768] -> WoBT bf16 [768][4128]
// ---------------------------------------------------------------------------
__global__ __launch_bounds__(256) void convert_wo_kernel(
    const float* __restrict__ Wo,
    const float* __restrict__ bo,
    uint16_t* __restrict__ wobt)
{
    __shared__ float tile[32][65];
    int bid = blockIdx.x;
    int kt = bid / 12;
    int nb = bid % 12;
    int t = threadIdx.x;
    {
        int rr = t >> 3;
        int c0 = (t & 7) * 8;
        int kg = kt * 32 + rr;
        const float* src = (kg < 4096 ? Wo + (size_t)kg * DLLM
                                      : bo + (size_t)(kg - 4096) * DLLM)
                           + nb * 64 + c0;
        float4 v0 = *(const float4*)src;
        float4 v1 = *(const float4*)(src + 4);
        tile[rr][c0 + 0] = v0.x; tile[rr][c0 + 1] = v0.y;
        tile[rr][c0 + 2] = v0.z; tile[rr][c0 + 3] = v0.w;
        tile[rr][c0 + 4] = v1.x; tile[rr][c0 + 5] = v1.y;
        tile[rr][c0 + 6] = v1.z; tile[rr][c0 + 7] = v1.w;
    }
    __syncthreads();
    {
        int n  = t >> 2;
        int k0 = (t & 3) * 8;
        uint4 u;
        u.x = pack2(tile[k0 + 0][n], tile[k0 + 1][n]);
        u.y = pack2(tile[k0 + 2][n], tile[k0 + 3][n]);
        u.z = pack2(tile[k0 + 4][n], tile[k0 + 5][n]);
        u.w = pack2(tile[k0 + 6][n], tile[k0 + 7][n]);
        *(uint4*)&wobt[((size_t)(nb * 64 + n)) * KP + kt * 32 + k0] = u;
    }
}

// ---------------------------------------------------------------------------
// Kernel 4b: MFMA GEMM. out[4096,768] = wout(bf16)[4096,4128] @ WoBT^T
// ---------------------------------------------------------------------------
__global__ __launch_bounds__(256) void fgemm_mfma_kernel(
    const uint16_t* __restrict__ wout,   // A  [4096][4128] bf16
    const uint16_t* __restrict__ wobt,   // B^T [768][4128] bf16
    float* __restrict__ out)             // [4096][768] fp32
{
    __shared__ short As[2][2048];
    __shared__ short Bs[2][2048];

    int bid = blockIdx.x;
    int swz = (bid & 7) * 96 + (bid >> 3);
    int mb = swz / 12;
    int nb = swz - mb * 12;

    int tid  = threadIdx.x;
    int lane = tid & 63;
    int w    = tid >> 6;
    int wr   = w >> 1;
    int wc   = w & 1;

    int r16 = lane & 15;
    int kp  = lane >> 4;

    const uint16_t* aptr = wout + ((size_t)(mb * 64 + w * 16 + r16)) * KP + kp * 8;
    const uint16_t* bptr = wobt + ((size_t)(nb * 64 + w * 16 + r16)) * KP + kp * 8;

    short* adst[2] = { &As[0][w * 512], &As[1][w * 512] };
    short* bdst[2] = { &Bs[0][w * 512], &Bs[1][w * 512] };

    f32x4 acc[2][2] = {};

    gload_lds16(aptr, adst[0]);
    gload_lds16(bptr, bdst[0]);
    __syncthreads();

    int cur = 0;
    for (int kt = 0; kt < 129; ++kt) {
        if (kt < 128) {
            gload_lds16(aptr + (size_t)(kt + 1) * 32, adst[cur ^ 1]);
            gload_lds16(bptr + (size_t)(kt + 1) * 32, bdst[cur ^ 1]);
        }
        const short* Ab = As[cur];
        const short* Bb = Bs[cur];
        bf16x8 a0 = *(const bf16x8*)(Ab + (wr * 2 + 0) * 512 + lane * 8);
        bf16x8 a1 = *(const bf16x8*)(Ab + (wr * 2 + 1) * 512 + lane * 8);
        bf16x8 b0 = *(const bf16x8*)(Bb + (wc * 2 + 0) * 512 + lane * 8);
        bf16x8 b1 = *(const bf16x8*)(Bb + (wc * 2 + 1) * 512 + lane * 8);
        acc[0][0] = __builtin_amdgcn_mfma_f32_16x16x32_bf16(a0, b0, acc[0][0], 0, 0, 0);
        acc[0][1] = __builtin_amdgcn_mfma_f32_16x16x32_bf16(a0, b1, acc[0][1], 0, 0, 0);
        acc[1][0] = __builtin_amdgcn_mfma_f32_16x16x32_bf16(a1, b0, acc[1][0], 0, 0, 0);
        acc[1][1] = __builtin_amdgcn_mfma_f32_16x16x32_bf16(a1, b1, acc[1][1], 0, 0, 0);
        __syncthreads();
        cur ^= 1;
    }

    int mbase = mb * 64 + wr * 32 + (lane >> 4) * 4;
    int nbase = nb * 64 + wc * 32 + (lane & 15);
#pragma unroll
    for (int fm = 0; fm < 2; ++fm)
#pragma unroll
        for (int fn = 0; fn < 2; ++fn)
#pragma unroll
            for (int r = 0; r < 4; ++r)
                out[(size_t)(mbase + fm * 16 + r) * DLLM + nbase + fn * 16] =
                    acc[fm][fn][r];
}

// ---------------------------------------------------------------------------
extern "C" void kernel_launch(void* const* d_in, const int* in_sizes, int n_in,
                              void* d_out, int out_size, void* d_ws, size_t ws_size,
                              hipStream_t stream) {
    const float* topk  = (const float*)d_in[0];  // (32,100,768)
    const float* ts    = (const float*)d_in[1];  // (64,64,128)
    const float* probs = (const float*)d_in[2];  // (64,64,32)
    const float* Wq    = (const float*)d_in[3];  // (32,128,129)
    const float* Wk    = (const float*)d_in[4];  // (32,128,769)
    const float* Wv    = (const float*)d_in[5];  // (32,128,769)
    const float* Wo    = (const float*)d_in[6];  // (32,128,768)
    const float* bo    = (const float*)d_in[7];  // (32,768)
    float* out = (float*)d_out;

    // workspace (uint16): kbuf | vbufT | qbuf | wout   (~69.3 MB)
    uint16_t* ws    = (uint16_t*)d_ws;
    uint16_t* kbuf  = ws;                          // 32*112*128 = 458752
    uint16_t* vbufT = ws + 458752;                 // 32*128*128 = 524288
    uint16_t* qbuf  = ws + 983040;                 // 32*4096*128 = 16777216
    uint16_t* wout  = ws + 983040 + 16777216;      // 4096*4128 = 16904192
    // overlays inside wout region (all dead before attn writes wout):
    uint16_t* tsbf   = wout;                       // 524288   (dead after q_proj)
    uint16_t* wqbf   = wout + 524288;              // 524288   (dead after q_proj)
    uint16_t* topkbf = wout + 1048576;             // 2457600  (dead after kv_mfma)
    uint16_t* wkbf   = wout + 1048576 + 2457600;   // 3145728  (dead after kv_mfma)
    uint16_t* wvbf   = wout + 1048576 + 2457600 + 3145728;  // 3145728, ends 9797632
    // overlay inside qbuf region (dead after attn):
    uint16_t* wobt = qbuf;                         // 768*4128

    convert_in_kernel<<<4096, 256, 0, stream>>>(ts, Wq, tsbf, wqbf);
    convert_kv_kernel<<<11392, 256, 0, stream>>>(topk, Wk, Wv, topkbf, wkbf, wvbf);
    kv_mfma_kernel<<<256, 256, 0, stream>>>(topkbf, wkbf, wvbf, Wk, Wv, kbuf, vbufT);
    q_proj_mfma_kernel<<<4096, 256, 0, stream>>>(tsbf, wqbf, Wq, qbuf);
    attn_mfma_kernel<<<2048, 256, 0, stream>>>(qbuf, kbuf, vbufT, probs, wout);
    convert_wo_kernel<<<1548, 256, 0, stream>>>(Wo, bo, wobt);
    fgemm_mfma_kernel<<<768, 256, 0, stream>>>(wout, wobt, out);
}

// Round 7
// 169.872 us; speedup vs baseline: 5.9155x; 1.1300x over previous
//
#include <hip/hip_runtime.h>
#include <stdint.h>

// Dims
#define NB 64
#define NL 64
#define NC 32
#define NK 100
#define NH 8
#define DKEY 16
#define DM 128
#define NG 128       // H*DKEY
#define DLLM 768
#define KP 4128      // 4096 + 32 (probs tail) : wout row stride
#define TEMP 0.25f   // 1/sqrt(16)

typedef __attribute__((ext_vector_type(8))) short bf16x8;
typedef __attribute__((ext_vector_type(4))) short bf16x4;
typedef __attribute__((ext_vector_type(4))) float f32x4;

typedef uint32_t __attribute__((address_space(1))) gu32;
typedef uint32_t __attribute__((address_space(3))) lu32;

__device__ __forceinline__ void gload_lds16(const void* g, void* l) {
    __builtin_amdgcn_global_load_lds((const gu32*)g, (lu32*)l, 16, 0, 0);
}

// ---------- bf16 helpers ----------
__device__ __forceinline__ uint16_t f2bf(float f) {
    union { float f; uint32_t i; } x; x.f = f;
    uint32_t r = x.i + 0x7FFFu + ((x.i >> 16) & 1u);
    return (uint16_t)(r >> 16);
}
__device__ __forceinline__ uint32_t pack2(float lo, float hi) {
    return (uint32_t)f2bf(lo) | ((uint32_t)f2bf(hi) << 16);
}
__device__ __forceinline__ uint32_t cvtpk_bf16(float lo, float hi) {
    uint32_t r;
    asm("v_cvt_pk_bf16_f32 %0, %1, %2" : "=v"(r) : "v"(lo), "v"(hi));
    return r;
}

// ---------------------------------------------------------------------------
// Kernel 0: convert ts and Wq (matmul part) to bf16.
// ---------------------------------------------------------------------------
__global__ __launch_bounds__(256) void convert_in_kernel(
    const float* __restrict__ ts,
    const float* __restrict__ Wq,
    uint16_t* __restrict__ tsbf,
    uint16_t* __restrict__ wqbf)
{
    int i = blockIdx.x * 256 + threadIdx.x;
    if (i < 524288) {
        tsbf[i] = f2bf(ts[i]);
    } else {
        int j = i - 524288;
        wqbf[j] = f2bf(Wq[(j >> 7) * 129 + (j & 127)]);
    }
}

// ---------------------------------------------------------------------------
// Kernel 0b: convert topk / Wk / Wv (matmul parts) to bf16.
// ---------------------------------------------------------------------------
__global__ __launch_bounds__(256) void convert_kv_kernel(
    const float* __restrict__ topk,
    const float* __restrict__ Wk,
    const float* __restrict__ Wv,
    uint16_t* __restrict__ topkbf,
    uint16_t* __restrict__ wkbf,
    uint16_t* __restrict__ wvbf)
{
    int r = blockIdx.x;
    int t = threadIdx.x;
    if (r < 3200) {
        if (t < 192) {
            float4 v = *(const float4*)(topk + (size_t)r * 768 + t * 4);
            uint2 u;
            u.x = pack2(v.x, v.y);
            u.y = pack2(v.z, v.w);
            *(uint2*)(topkbf + (size_t)r * 768 + t * 4) = u;
        }
    } else {
        int rr = r - 3200;
        const float* src;
        uint16_t* dst;
        if (rr < 4096) {
            src = Wk + (size_t)rr * 769;
            dst = wkbf + (size_t)rr * 768;
        } else {
            rr -= 4096;
            src = Wv + (size_t)rr * 769;
            dst = wvbf + (size_t)rr * 768;
        }
#pragma unroll
        for (int i = 0; i < 3; ++i)
            dst[t + 256 * i] = f2bf(src[t + 256 * i]);
    }
}

// ---------------------------------------------------------------------------
// Kernel 1: K/V projection via MFMA (unchanged from round 6).
// ---------------------------------------------------------------------------
__global__ __launch_bounds__(256) void kv_mfma_kernel(
    const uint16_t* __restrict__ topkbf,  // [3200][768]
    const uint16_t* __restrict__ wkbf,    // [32*128][768]
    const uint16_t* __restrict__ wvbf,    // [32*128][768]
    const float* __restrict__ Wk,         // bias col
    const float* __restrict__ Wv,         // bias col
    uint16_t* __restrict__ kbuf,          // [32][112][128]
    uint16_t* __restrict__ vbufT)         // [32][128][128]
{
    __shared__ short As[2][2048];
    __shared__ short Bs[2][2048];

    int bid = blockIdx.x;
    int nb = bid & 1;
    int mb = (bid >> 1) & 1;
    int c  = (bid >> 2) & 31;
    int which = bid >> 7;     // 0=K, 1=V

    int tid  = threadIdx.x;
    int lane = tid & 63;
    int w    = tid >> 6;
    int wr   = w >> 1;
    int wc   = w & 1;
    int r16  = lane & 15;
    int kp   = lane >> 4;

    int arow = mb * 64 + w * 16 + r16;
    int brow = nb * 64 + w * 16 + r16;
    const uint16_t* aptr;
    const uint16_t* bptr;
    if (which == 0) {
        aptr = topkbf + ((size_t)(c * 100 + arow)) * 768 + kp * 8;
        bptr = wkbf   + ((size_t)(c * 128 + brow)) * 768 + kp * 8;
    } else {
        aptr = wvbf   + ((size_t)(c * 128 + arow)) * 768 + kp * 8;
        bptr = topkbf + ((size_t)(c * 100 + brow)) * 768 + kp * 8;
    }

    short* adst[2] = { &As[0][w * 512], &As[1][w * 512] };
    short* bdst[2] = { &Bs[0][w * 512], &Bs[1][w * 512] };

    f32x4 acc[2][2] = {};

    gload_lds16(aptr, adst[0]);
    gload_lds16(bptr, bdst[0]);
    __syncthreads();

    int cur = 0;
    for (int kt = 0; kt < 24; ++kt) {
        if (kt < 23) {
            gload_lds16(aptr + (kt + 1) * 32, adst[cur ^ 1]);
            gload_lds16(bptr + (kt + 1) * 32, bdst[cur ^ 1]);
        }
        const short* Ab = As[cur];
        const short* Bb = Bs[cur];
        bf16x8 a0 = *(const bf16x8*)(Ab + (wr * 2 + 0) * 512 + lane * 8);
        bf16x8 a1 = *(const bf16x8*)(Ab + (wr * 2 + 1) * 512 + lane * 8);
        bf16x8 b0 = *(const bf16x8*)(Bb + (wc * 2 + 0) * 512 + lane * 8);
        bf16x8 b1 = *(const bf16x8*)(Bb + (wc * 2 + 1) * 512 + lane * 8);
        acc[0][0] = __builtin_amdgcn_mfma_f32_16x16x32_bf16(a0, b0, acc[0][0], 0, 0, 0);
        acc[0][1] = __builtin_amdgcn_mfma_f32_16x16x32_bf16(a0, b1, acc[0][1], 0, 0, 0);
        acc[1][0] = __builtin_amdgcn_mfma_f32_16x16x32_bf16(a1, b0, acc[1][0], 0, 0, 0);
        acc[1][1] = __builtin_amdgcn_mfma_f32_16x16x32_bf16(a1, b1, acc[1][1], 0, 0, 0);
        __syncthreads();
        cur ^= 1;
    }

    int mbase = mb * 64 + wr * 32 + (lane >> 4) * 4;
    int nbase = nb * 64 + wc * 32 + (lane & 15);

    if (which == 0) {
        float bias0 = Wk[((size_t)c * 128 + nbase)      * 769 + 768];
        float bias1 = Wk[((size_t)c * 128 + nbase + 16) * 769 + 768];
#pragma unroll
        for (int fm = 0; fm < 2; ++fm)
#pragma unroll
            for (int r = 0; r < 4; ++r) {
                int mrow = mbase + fm * 16 + r;
                if (mrow < 112) {
                    kbuf[((size_t)c * 112 + mrow) * 128 + nbase]      = f2bf(acc[fm][0][r] + bias0);
                    kbuf[((size_t)c * 112 + mrow) * 128 + nbase + 16] = f2bf(acc[fm][1][r] + bias1);
                }
            }
    } else {
#pragma unroll
        for (int fm = 0; fm < 2; ++fm)
#pragma unroll
            for (int r = 0; r < 4; ++r) {
                int grow = mbase + fm * 16 + r;
                float bias = Wv[((size_t)c * 128 + grow) * 769 + 768];
#pragma unroll
                for (int fn = 0; fn < 2; ++fn) {
                    int ncol = nbase + fn * 16;
                    uint16_t val = (ncol < NK) ? f2bf(acc[fm][fn][r] + bias) : (uint16_t)0;
                    vbufT[((size_t)c * 128 + grow) * 128 + ncol] = val;
                }
            }
    }
}

// ---------------------------------------------------------------------------
// Kernel 2: Q projection via MFMA (unchanged from round 6).
// ---------------------------------------------------------------------------
__global__ __launch_bounds__(256) void q_proj_mfma_kernel(
    const uint16_t* __restrict__ tsbf,   // [4096][128]
    const uint16_t* __restrict__ wqbf,   // [32][128][128]
    const float* __restrict__ Wq,        // bias col
    uint16_t* __restrict__ qbuf)
{
    __shared__ short As[2][2048];
    __shared__ short Bs[2][2048];

    int bid = blockIdx.x;
    int mb = bid & 63;
    int nb = (bid >> 6) & 1;
    int c  = bid >> 7;

    int tid  = threadIdx.x;
    int lane = tid & 63;
    int w    = tid >> 6;
    int wr   = w >> 1;
    int wc   = w & 1;

    int r16 = lane & 15;
    int kp  = lane >> 4;

    const uint16_t* aptr = tsbf + ((size_t)(mb * 64 + w * 16 + r16)) * 128 + kp * 8;
    const uint16_t* bptr = wqbf + ((size_t)(c * 128 + nb * 64 + w * 16 + r16)) * 128 + kp * 8;

    short* adst[2] = { &As[0][w * 512], &As[1][w * 512] };
    short* bdst[2] = { &Bs[0][w * 512], &Bs[1][w * 512] };

    f32x4 acc[2][2] = {};

    gload_lds16(aptr, adst[0]);
    gload_lds16(bptr, bdst[0]);
    __syncthreads();

    int cur = 0;
    for (int kt = 0; kt < 4; ++kt) {
        if (kt < 3) {
            gload_lds16(aptr + (kt + 1) * 32, adst[cur ^ 1]);
            gload_lds16(bptr + (kt + 1) * 32, bdst[cur ^ 1]);
        }
        const short* Ab = As[cur];
        const short* Bb = Bs[cur];
        bf16x8 a0 = *(const bf16x8*)(Ab + (wr * 2 + 0) * 512 + lane * 8);
        bf16x8 a1 = *(const bf16x8*)(Ab + (wr * 2 + 1) * 512 + lane * 8);
        bf16x8 b0 = *(const bf16x8*)(Bb + (wc * 2 + 0) * 512 + lane * 8);
        bf16x8 b1 = *(const bf16x8*)(Bb + (wc * 2 + 1) * 512 + lane * 8);
        acc[0][0] = __builtin_amdgcn_mfma_f32_16x16x32_bf16(a0, b0, acc[0][0], 0, 0, 0);
        acc[0][1] = __builtin_amdgcn_mfma_f32_16x16x32_bf16(a0, b1, acc[0][1], 0, 0, 0);
        acc[1][0] = __builtin_amdgcn_mfma_f32_16x16x32_bf16(a1, b0, acc[1][0], 0, 0, 0);
        acc[1][1] = __builtin_amdgcn_mfma_f32_16x16x32_bf16(a1, b1, acc[1][1], 0, 0, 0);
        __syncthreads();
        cur ^= 1;
    }

    int mbase = mb * 64 + wr * 32 + (lane >> 4) * 4;
    int nbase = nb * 64 + wc * 32 + (lane & 15);
#pragma unroll
    for (int fn = 0; fn < 2; ++fn) {
        int ncol = nbase + fn * 16;
        float bias = Wq[((size_t)c * 128 + ncol) * 129 + 128];
#pragma unroll
        for (int fm = 0; fm < 2; ++fm)
#pragma unroll
            for (int r = 0; r < 4; ++r)
                qbuf[((size_t)c * 4096 + mbase + fm * 16 + r) * 128 + ncol] =
                    f2bf(acc[fm][fn][r] + bias);
    }
}

// ---------------------------------------------------------------------------
// Kernel 3: MFMA attention (unchanged from round 6).
// ---------------------------------------------------------------------------
__global__ __launch_bounds__(256) void attn_mfma_kernel(
    const uint16_t* __restrict__ qbuf,
    const uint16_t* __restrict__ kbuf,
    const uint16_t* __restrict__ vbufT,
    const float* __restrict__ probs,
    uint16_t* __restrict__ wout)
{
    __shared__ short Pl[4][64][128];   // 65536 B == 64 KiB exactly

    int bid = blockIdx.x;
    int c = bid >> 6;
    int b = bid & 63;
    int tid = threadIdx.x;
    int lane = tid & 63;
    int w = tid >> 6;
    int g = lane >> 4;        // 0..3
    int l15 = lane & 15;
    int swz = l15 << 4;       // 16B-block XOR swizzle key

    float pr_tok = probs[((size_t)b * 64 + lane) * NC + c];

    uint8_t* Pb = (uint8_t*)&Pl[w][0][0];
    bf16x8 zf = {};

    for (int hh = 0; hh < 2; ++hh) {
        int h = w * 2 + hh;

        bf16x8 qb[4];
#pragma unroll
        for (int nt = 0; nt < 4; ++nt) {
            if (g < 2)
                qb[nt] = *(const bf16x8*)&qbuf[((size_t)c * 4096 + b * 64 + nt * 16 + l15) * 128 + h * 16 + g * 8];
            else
                qb[nt] = zf;
        }

        float psum[4] = {0.f, 0.f, 0.f, 0.f};
#pragma unroll
        for (int mt = 0; mt < 7; ++mt) {
            bf16x8 ka;
            if (g < 2)
                ka = *(const bf16x8*)&kbuf[((size_t)c * 112 + mt * 16 + l15) * 128 + h * 16 + g * 8];
            else
                ka = zf;
            f32x4 s[4];
#pragma unroll
            for (int nt = 0; nt < 4; ++nt)
                s[nt] = __builtin_amdgcn_mfma_f32_16x16x32_bf16(ka, qb[nt], (f32x4){0.f,0.f,0.f,0.f}, 0, 0, 0);
            bool valid = (mt < 6) || (g == 0);
#pragma unroll
            for (int nt = 0; nt < 4; ++nt) {
                float p0 = valid ? __expf(s[nt][0] * TEMP) : 0.f;
                float p1 = valid ? __expf(s[nt][1] * TEMP) : 0.f;
                float p2 = valid ? __expf(s[nt][2] * TEMP) : 0.f;
                float p3 = valid ? __expf(s[nt][3] * TEMP) : 0.f;
                psum[nt] += (p0 + p1) + (p2 + p3);
                union { uint32_t u[2]; bf16x4 v; } pk;
                pk.u[0] = cvtpk_bf16(p0, p1);
                pk.u[1] = cvtpk_bf16(p2, p3);
                int l = nt * 16 + l15;
                *(bf16x4*)(Pb + l * 256 + ((mt * 32 + g * 8) ^ swz)) = pk.v;
            }
        }
        {
            bf16x4 z4 = {};
#pragma unroll
            for (int nt = 0; nt < 4; ++nt) {
                int l = nt * 16 + l15;
                *(bf16x4*)(Pb + l * 256 + ((224 + g * 8) ^ swz)) = z4;
            }
        }
        __syncthreads();

        float rsum[4];
#pragma unroll
        for (int nt = 0; nt < 4; ++nt) {
            float t = psum[nt];
            t += __shfl_xor(t, 16);
            t += __shfl_xor(t, 32);
            rsum[nt] = __builtin_amdgcn_rcpf(t);
        }

        f32x4 oacc[4] = {};
#pragma unroll
        for (int ch = 0; ch < 4; ++ch) {
            bf16x8 vb = *(const bf16x8*)&vbufT[((size_t)c * 128 + h * 16 + l15) * 128 + ch * 32 + g * 8];
#pragma unroll
            for (int mt = 0; mt < 4; ++mt) {
                int l = mt * 16 + l15;
                bf16x8 pa = *(const bf16x8*)(Pb + l * 256 + ((ch * 64 + g * 16) ^ swz));
                oacc[mt] = __builtin_amdgcn_mfma_f32_16x16x32_bf16(pa, vb, oacc[mt], 0, 0, 0);
            }
        }
#pragma unroll
        for (int mt = 0; mt < 4; ++mt) {
#pragma unroll
            for (int r = 0; r < 4; ++r) {
                int l = mt * 16 + g * 4 + r;
                float sc = __shfl(pr_tok, l) * __shfl(rsum[mt], g * 4 + r);
                wout[((size_t)b * 64 + l) * KP + c * 128 + h * 16 + l15] =
                    f2bf(oacc[mt][r] * sc);
            }
        }
        __syncthreads();
    }
    if (tid < 64)
        wout[((size_t)b * 64 + tid) * KP + 4096 + c] = f2bf(pr_tok);
}

// ---------------------------------------------------------------------------
// Kernel 4a: transpose+convert [Wo;bo] fp32 [4128][768] -> WoBT bf16 [768][4128]
// ---------------------------------------------------------------------------
__global__ __launch_bounds__(256) void convert_wo_kernel(
    const float* __restrict__ Wo,
    const float* __restrict__ bo,
    uint16_t* __restrict__ wobt)
{
    __shared__ float tile[32][65];
    int bid = blockIdx.x;
    int kt = bid / 12;
    int nb = bid % 12;
    int t = threadIdx.x;
    {
        int rr = t >> 3;
        int c0 = (t & 7) * 8;
        int kg = kt * 32 + rr;
        const float* src = (kg < 4096 ? Wo + (size_t)kg * DLLM
                                      : bo + (size_t)(kg - 4096) * DLLM)
                           + nb * 64 + c0;
        float4 v0 = *(const float4*)src;
        float4 v1 = *(const float4*)(src + 4);
        tile[rr][c0 + 0] = v0.x; tile[rr][c0 + 1] = v0.y;
        tile[rr][c0 + 2] = v0.z; tile[rr][c0 + 3] = v0.w;
        tile[rr][c0 + 4] = v1.x; tile[rr][c0 + 5] = v1.y;
        tile[rr][c0 + 6] = v1.z; tile[rr][c0 + 7] = v1.w;
    }
    __syncthreads();
    {
        int n  = t >> 2;
        int k0 = (t & 3) * 8;
        uint4 u;
        u.x = pack2(tile[k0 + 0][n], tile[k0 + 1][n]);
        u.y = pack2(tile[k0 + 2][n], tile[k0 + 3][n]);
        u.z = pack2(tile[k0 + 4][n], tile[k0 + 5][n]);
        u.w = pack2(tile[k0 + 6][n], tile[k0 + 7][n]);
        *(uint4*)&wobt[((size_t)(nb * 64 + n)) * KP + kt * 32 + k0] = u;
    }
}

// ---------------------------------------------------------------------------
// Kernel 4b: split-K MFMA GEMM (m97-style 128x128 tile).
// part[h][4096][768] fp32 = wout[:, kh] @ WoBT[:, kh]^T for K-halves h=0,1
// (h=0: 64 K-steps = k 0..2047; h=1: 65 K-steps = k 2048..4127).
// 4 waves in 2x2, each wave 64x64 (4x4 16x16x32 frags, 16 MFMA/K-step).
// Fragment-major LDS [rowgroup(8)][kchunk(4)][row16][8], staged by two
// gload_lds16 per operand (linear dest, conflict-free b128 reads).
// grid = 2*32*6 = 384 blocks, XCD-swizzled (384 % 8 == 0).
// ---------------------------------------------------------------------------
__global__ __launch_bounds__(256) void fgemm_splitk_kernel(
    const uint16_t* __restrict__ wout,   // A  [4096][4128] bf16
    const uint16_t* __restrict__ wobt,   // B^T [768][4128] bf16
    float* __restrict__ part)            // [2][4096][768] fp32
{
    __shared__ short As[2][4096];
    __shared__ short Bs[2][4096];

    int bid = blockIdx.x;
    int swz = (bid & 7) * 48 + (bid >> 3);   // bijective on [0,384)
    int h  = swz / 192;                       // k-half
    int rr = swz - h * 192;
    int mb = rr / 6;                          // 0..31
    int nb = rr - mb * 6;                     // 0..5

    int tid  = threadIdx.x;
    int lane = tid & 63;
    int w    = tid >> 6;
    int wr   = w >> 1;        // wave row (64 m)
    int wc   = w & 1;         // wave col (64 n)

    // staging source (thread-linear fragment-major): thread t covers LDS
    // shorts t*8 (rowgroups 0..3) and 2048+t*8 (rowgroups 4..7).
    int sg = tid >> 6;
    int skp = (tid >> 4) & 3;
    int sr = tid & 15;
    const uint16_t* aptr = wout + ((size_t)(mb * 128 + sg * 16 + sr)) * KP + h * 2048 + skp * 8;
    const uint16_t* bptr = wobt + ((size_t)(nb * 128 + sg * 16 + sr)) * KP + h * 2048 + skp * 8;

    short* adst[2] = { &As[0][w * 512], &As[1][w * 512] };
    short* bdst[2] = { &Bs[0][w * 512], &Bs[1][w * 512] };

    int nkt = h ? 65 : 64;

    f32x4 acc[4][4] = {};

    // prologue: stage K-step 0
    gload_lds16(aptr, adst[0]);
    gload_lds16(aptr + (size_t)64 * KP, adst[0] + 2048);
    gload_lds16(bptr, bdst[0]);
    gload_lds16(bptr + (size_t)64 * KP, bdst[0] + 2048);
    __syncthreads();

    int cur = 0;
    for (int kt = 0; kt < nkt; ++kt) {
        if (kt + 1 < nkt) {
            const uint16_t* ap = aptr + (size_t)(kt + 1) * 32;
            const uint16_t* bp = bptr + (size_t)(kt + 1) * 32;
            gload_lds16(ap, adst[cur ^ 1]);
            gload_lds16(ap + (size_t)64 * KP, adst[cur ^ 1] + 2048);
            gload_lds16(bp, bdst[cur ^ 1]);
            gload_lds16(bp + (size_t)64 * KP, bdst[cur ^ 1] + 2048);
        }
        const short* Ab = As[cur];
        const short* Bb = Bs[cur];
        bf16x8 av[4], bv[4];
#pragma unroll
        for (int m = 0; m < 4; ++m)
            av[m] = *(const bf16x8*)(Ab + (wr * 4 + m) * 512 + lane * 8);
#pragma unroll
        for (int n = 0; n < 4; ++n)
            bv[n] = *(const bf16x8*)(Bb + (wc * 4 + n) * 512 + lane * 8);
#pragma unroll
        for (int m = 0; m < 4; ++m)
#pragma unroll
            for (int n = 0; n < 4; ++n)
                acc[m][n] = __builtin_amdgcn_mfma_f32_16x16x32_bf16(av[m], bv[n], acc[m][n], 0, 0, 0);
        __syncthreads();
        cur ^= 1;
    }

    // epilogue: C/D layout col = lane&15, row = (lane>>4)*4 + reg
    float* P = part + (size_t)h * (4096 * 768);
    int mbase = mb * 128 + wr * 64 + (lane >> 4) * 4;
    int nbase = nb * 128 + wc * 64 + (lane & 15);
#pragma unroll
    for (int m = 0; m < 4; ++m)
#pragma unroll
        for (int n = 0; n < 4; ++n)
#pragma unroll
            for (int r = 0; r < 4; ++r)
                P[(size_t)(mbase + m * 16 + r) * DLLM + nbase + n * 16] =
                    acc[m][n][r];
}

// ---------------------------------------------------------------------------
// Kernel 4c: reduce the two K-half partials into the fp32 output.
// grid = 3072 x 256, one float4 per thread (exact cover of 4096*768).
// ---------------------------------------------------------------------------
__global__ __launch_bounds__(256) void reduce_out_kernel(
    const float* __restrict__ part,
    float* __restrict__ out)
{
    int i = (blockIdx.x * 256 + threadIdx.x) * 4;
    float4 a = *(const float4*)(part + i);
    float4 b = *(const float4*)(part + 4096 * 768 + i);
    float4 s;
    s.x = a.x + b.x; s.y = a.y + b.y; s.z = a.z + b.z; s.w = a.w + b.w;
    *(float4*)(out + i) = s;
}

// ---------------------------------------------------------------------------
extern "C" void kernel_launch(void* const* d_in, const int* in_sizes, int n_in,
                              void* d_out, int out_size, void* d_ws, size_t ws_size,
                              hipStream_t stream) {
    const float* topk  = (const float*)d_in[0];  // (32,100,768)
    const float* ts    = (const float*)d_in[1];  // (64,64,128)
    const float* probs = (const float*)d_in[2];  // (64,64,32)
    const float* Wq    = (const float*)d_in[3];  // (32,128,129)
    const float* Wk    = (const float*)d_in[4];  // (32,128,769)
    const float* Wv    = (const float*)d_in[5];  // (32,128,769)
    const float* Wo    = (const float*)d_in[6];  // (32,128,768)
    const float* bo    = (const float*)d_in[7];  // (32,768)
    float* out = (float*)d_out;

    // workspace (uint16): kbuf | vbufT | qbuf | wout   (~69.3 MB)
    uint16_t* ws    = (uint16_t*)d_ws;
    uint16_t* kbuf  = ws;                          // 32*112*128 = 458752
    uint16_t* vbufT = ws + 458752;                 // 32*128*128 = 524288
    uint16_t* qbuf  = ws + 983040;                 // 32*4096*128 = 16777216
    uint16_t* wout  = ws + 983040 + 16777216;      // 4096*4128 = 16904192
    // overlays inside wout region (all dead before attn writes wout):
    uint16_t* tsbf   = wout;                       // 524288   (dead after q_proj)
    uint16_t* wqbf   = wout + 524288;              // 524288   (dead after q_proj)
    uint16_t* topkbf = wout + 1048576;             // 2457600  (dead after kv_mfma)
    uint16_t* wkbf   = wout + 1048576 + 2457600;   // 3145728  (dead after kv_mfma)
    uint16_t* wvbf   = wout + 1048576 + 2457600 + 3145728;  // 3145728, ends 9797632
    // overlays inside qbuf region (dead after attn):
    uint16_t* wobt = qbuf;                         // 768*4128 = 3170304 shorts
    float*    part = (float*)(qbuf + 3170304);     // 2*4096*768 fp32 = 25.2 MB
                                                   // (3170304+12582912 <= 16777216 ✓)

    convert_in_kernel<<<4096, 256, 0, stream>>>(ts, Wq, tsbf, wqbf);
    convert_kv_kernel<<<11392, 256, 0, stream>>>(topk, Wk, Wv, topkbf, wkbf, wvbf);
    kv_mfma_kernel<<<256, 256, 0, stream>>>(topkbf, wkbf, wvbf, Wk, Wv, kbuf, vbufT);
    q_proj_mfma_kernel<<<4096, 256, 0, stream>>>(tsbf, wqbf, Wq, qbuf);
    attn_mfma_kernel<<<2048, 256, 0, stream>>>(qbuf, kbuf, vbufT, probs, wout);
    convert_wo_kernel<<<1548, 256, 0, stream>>>(Wo, bo, wobt);
    fgemm_splitk_kernel<<<384, 256, 0, stream>>>(wout, wobt, part);
    reduce_out_kernel<<<3072, 256, 0, stream>>>(part, out);
}